// Round 5
// baseline (945.761 us; speedup 1.0000x reference)
//
#include <hip/hip_runtime.h>
#include <type_traits>

// Problem constants
#define N_ATOMS 512
#define C_DIM   64
#define K_SP    5
#define TS      16      // signals per block
#define HROW    512     // H LDS row stride (all H accesses are row-contiguous)

// ws layout (floats):
//   dn   [0,      32768)   : (64 x 512) row-major [c][n]
//   dnT  [32768,  65536)   : (512 x 64) [n][c]
//   G    [65536, 327680)   : (512 x 512)
//   lossAcc (double) at byte offset 1310720; counter (u32) at 1310728

// ---------------------------------------------------------------------------
// Wave64 DPP reductions (all-VALU; replaces ds_swizzle butterfly ~450cy -> ~50cy)
// quad_perm(1,0,3,2)=0xB1 (xor1), quad_perm(2,3,0,1)=0x4E (xor2),
// row_half_mirror=0x141, row_mirror=0x140, row_bcast15=0x142, row_bcast31=0x143.
// After the chain lane 63 holds the full-wave result; readlane broadcasts it.
// ---------------------------------------------------------------------------
__device__ __forceinline__ unsigned wave_redmax_u32(unsigned u) {
  unsigned t;
  t = (unsigned)__builtin_amdgcn_update_dpp((int)u, (int)u, 0xB1, 0xF, 0xF, false); u = t > u ? t : u;
  t = (unsigned)__builtin_amdgcn_update_dpp((int)u, (int)u, 0x4E, 0xF, 0xF, false); u = t > u ? t : u;
  t = (unsigned)__builtin_amdgcn_update_dpp((int)u, (int)u, 0x141, 0xF, 0xF, false); u = t > u ? t : u;
  t = (unsigned)__builtin_amdgcn_update_dpp((int)u, (int)u, 0x140, 0xF, 0xF, false); u = t > u ? t : u;
  t = (unsigned)__builtin_amdgcn_update_dpp((int)u, (int)u, 0x142, 0xF, 0xF, false); u = t > u ? t : u;
  t = (unsigned)__builtin_amdgcn_update_dpp((int)u, (int)u, 0x143, 0xF, 0xF, false); u = t > u ? t : u;
  return (unsigned)__builtin_amdgcn_readlane((int)u, 63);
}
__device__ __forceinline__ unsigned wave_redmin_u32(unsigned u) {
  unsigned t;
  t = (unsigned)__builtin_amdgcn_update_dpp((int)u, (int)u, 0xB1, 0xF, 0xF, false); u = t < u ? t : u;
  t = (unsigned)__builtin_amdgcn_update_dpp((int)u, (int)u, 0x4E, 0xF, 0xF, false); u = t < u ? t : u;
  t = (unsigned)__builtin_amdgcn_update_dpp((int)u, (int)u, 0x141, 0xF, 0xF, false); u = t < u ? t : u;
  t = (unsigned)__builtin_amdgcn_update_dpp((int)u, (int)u, 0x140, 0xF, 0xF, false); u = t < u ? t : u;
  t = (unsigned)__builtin_amdgcn_update_dpp((int)u, (int)u, 0x142, 0xF, 0xF, false); u = t < u ? t : u;
  t = (unsigned)__builtin_amdgcn_update_dpp((int)u, (int)u, 0x143, 0xF, 0xF, false); u = t < u ? t : u;
  return (unsigned)__builtin_amdgcn_readlane((int)u, 63);
}

// ---------------------------------------------------------------------------
// Kernel 1: column norms + normalized dictionary (dn) + its transpose (dnT).
// ---------------------------------------------------------------------------
__global__ __launch_bounds__(64) void prep_norm_k(const float* __restrict__ dict,
                                                  float* __restrict__ dn,
                                                  float* __restrict__ dnT,
                                                  double* __restrict__ lossAcc,
                                                  unsigned int* __restrict__ cnt) {
#pragma clang fp contract(off)
  __shared__ float tile[64][65];
  const int t = threadIdx.x;
  const int n0 = blockIdx.x * 64;
  const int n = n0 + t;
  if (blockIdx.x == 0 && t == 0) { *lossAcc = 0.0; *cnt = 0u; }
  float s = 0.0f;
  for (int c = 0; c < C_DIM; ++c) {
    float v = dict[c * N_ATOMS + n];
    tile[t][c] = v;
    float sq = v * v;
    s = s + sq;
  }
  float m = fmaxf(sqrtf(s), 1e-10f);
  for (int c = 0; c < C_DIM; ++c) {
    float q = tile[t][c] / m;
    tile[t][c] = q;
    dn[c * N_ATOMS + n] = q;           // coalesced across lanes
  }
  __syncthreads();
  // dnT rows n0..n0+63, coalesced float4 stores
  for (int r = 0; r < 16; ++r) {
    int e = r * 64 + t;
    int nn = e >> 4, cc = (e & 15) * 4;
    float4 v = make_float4(tile[nn][cc], tile[nn][cc + 1], tile[nn][cc + 2], tile[nn][cc + 3]);
    *reinterpret_cast<float4*>(&dnT[(size_t)(n0 + nn) * C_DIM + cc]) = v;
  }
}

// ---------------------------------------------------------------------------
// Kernel 2: G = dn^T dn (512x512), f32 FMA chain sequential over c.
// Note G is BITWISE symmetric (same summation order for (i,j) and (j,i)) —
// phase 2 exploits this to read G[i][nsel] from the cached row nsel... and
// vice versa.
// ---------------------------------------------------------------------------
__global__ __launch_bounds__(256) void prep_gram_k(const float* __restrict__ dn,
                                                   float* __restrict__ G) {
#pragma clang fp contract(off)
  __shared__ float As[64][64];
  __shared__ float Bs[64][64];
  const int bi = blockIdx.x & 7, bj = blockIdx.x >> 3;
  const int tid = threadIdx.x;
  for (int r = 0; r < 16; ++r) {
    int e = r * 256 + tid;
    int c = e >> 6, i = e & 63;
    As[c][i] = dn[c * N_ATOMS + bi * 64 + i];
    Bs[c][i] = dn[c * N_ATOMS + bj * 64 + i];
  }
  __syncthreads();
  const int ti = tid & 15, tj = tid >> 4;
  float acc[4][4] = {};
  for (int c = 0; c < 64; ++c) {
    float a[4], b[4];
#pragma unroll
    for (int u = 0; u < 4; ++u) { a[u] = As[c][ti * 4 + u]; b[u] = Bs[c][tj * 4 + u]; }
#pragma unroll
    for (int u = 0; u < 4; ++u)
#pragma unroll
      for (int v = 0; v < 4; ++v) acc[u][v] = fmaf(a[u], b[v], acc[u][v]);
  }
  for (int u = 0; u < 4; ++u)
    for (int v = 0; v < 4; ++v)
      G[(size_t)(bi * 64 + ti * 4 + u) * N_ATOMS + bj * 64 + tj * 4 + v] = acc[u][v];
}

// ---------------------------------------------------------------------------
// Kernel 3: fused h_bar GEMM + batched OMP + outputs.
// Block = 16 signals, 256 threads = 4 waves, ~38 KB LDS (4 blocks/CU).
// Phase 2 critical path is pure VALU: DPP argmax; G values extracted from
// register-cached rows via readlane (G symmetric); the next row's global load
// is issued right after argmax and hides under the solves.
// ---------------------------------------------------------------------------
__global__ __launch_bounds__(256) void omp_main_k(const float* __restrict__ z,
                                                  const float* __restrict__ dn,
                                                  const float* __restrict__ dnT,
                                                  const float* __restrict__ Gm,
                                                  float* __restrict__ out0,
                                                  float* __restrict__ coeffs,
                                                  double* __restrict__ lossAcc,
                                                  unsigned int* __restrict__ cnt) {
#pragma clang fp contract(off)
  __shared__ float Xs[TS][68];                        // [sl][c], 68-stride: 16B-aligned rows
  __shared__ __align__(16) float UB[TS * HROW];       // 32 KB: dn chunk, then H[sl][atom]
  __shared__ int   IldsI[TS][K_SP];
  __shared__ float IldsX[TS][K_SP];

  const int tid   = threadIdx.x;
  const int sbase = blockIdx.x * TS;
  const int b     = sbase >> 10;
  const int hw0   = sbase & 1023;
  const float* zb = z + (size_t)b * 65536;

  // ---- stage Xs transposed (coalesced float4 in, scalar LDS writes) ----
  {
    int c = tid >> 2, slc0 = (tid & 3) * 4;
    float4 v = *reinterpret_cast<const float4*>(zb + c * 1024 + hw0 + slc0);
    Xs[slc0 + 0][c] = v.x; Xs[slc0 + 1][c] = v.y;
    Xs[slc0 + 2][c] = v.z; Xs[slc0 + 3][c] = v.w;
  }

  // ---- Phase 1: GEMM. thread: atoms {4*ia+r, 256+4*ia+r}, signals {4*js+u}
  const int ia4 = (tid & 63) * 4;
  const int js4 = (tid >> 6) * 4;
  float acc[8][4] = {};
#pragma unroll
  for (int cc = 0; cc < 4; ++cc) {
    __syncthreads();
    {
      const float* src = dn + cc * 8192;   // 16 rows x 512, reg-staged float4
#pragma unroll
      for (int r = 0; r < 8; ++r) {
        int off = (r * 256 + tid) * 4;
        *reinterpret_cast<float4*>(&UB[off]) = *reinterpret_cast<const float4*>(src + off);
      }
    }
    __syncthreads();
#pragma unroll
    for (int c4 = 0; c4 < 4; ++c4) {
      float xw[4][4];                       // [u][cl]
#pragma unroll
      for (int u = 0; u < 4; ++u) {
        float4 xq = *reinterpret_cast<const float4*>(&Xs[js4 + u][cc * 16 + c4 * 4]);
        xw[u][0] = xq.x; xw[u][1] = xq.y; xw[u][2] = xq.z; xw[u][3] = xq.w;
      }
#pragma unroll
      for (int cl = 0; cl < 4; ++cl) {
        const int c = c4 * 4 + cl;
        const float4 d0 = *reinterpret_cast<const float4*>(&UB[c * 512 + ia4]);
        const float4 d1 = *reinterpret_cast<const float4*>(&UB[c * 512 + 256 + ia4]);
        const float dv[8] = { d0.x, d0.y, d0.z, d0.w, d1.x, d1.y, d1.z, d1.w };
#pragma unroll
        for (int r = 0; r < 8; ++r)
#pragma unroll
          for (int u = 0; u < 4; ++u)
            acc[r][u] = fmaf(dv[r], xw[u][cl], acc[r][u]);   // sequential over global c
      }
    }
  }
  __syncthreads();
  // write H[sl][atom] (row-contiguous float4, conflict-free)
#pragma unroll
  for (int u = 0; u < 4; ++u) {
    const int sl = js4 + u;
    *reinterpret_cast<float4*>(&UB[sl * HROW + ia4]) =
        make_float4(acc[0][u], acc[1][u], acc[2][u], acc[3][u]);
    *reinterpret_cast<float4*>(&UB[sl * HROW + 256 + ia4]) =
        make_float4(acc[4][u], acc[5][u], acc[6][u], acc[7][u]);
  }
  __syncthreads();

  // ---- Phase 2: OMP (wave per signal, 4 signals per wave) ----
  const int lane = tid & 63;
  const int wid  = tid >> 6;
  double lsum = 0.0;

  for (int q = 0; q < 4; ++q) {
    const int sl = wid * 4 + q;
    float hb[8];
#pragma unroll
    for (int jb = 0; jb < 8; ++jb) hb[jb] = UB[sl * HROW + lane + 64 * jb];  // lane-consecutive

    unsigned selmask = 0;
    int   I[K_SP];
    float xs[K_SP];
    float yv[K_SP];
    float Lm[K_SP][K_SP];
    int   srtI[4];
    float GrowS[4][8];

    auto iter = [&](auto KC) {
      constexpr int k = decltype(KC)::value;
      float cur[8];
      if constexpr (k == 1) {
#pragma unroll
        for (int jb = 0; jb < 8; ++jb) cur[jb] = hb[jb];
      } else {
        // xs values aligned to sorted atom order (numpy sums beta j-ascending)
        float xsS[k - 1];
#pragma unroll
        for (int u = 0; u < k - 1; ++u) {
          float xv = 0.0f;
#pragma unroll
          for (int t = 0; t < k - 1; ++t) xv = (I[t] == srtI[u]) ? xs[t] : xv;
          xsS[u] = xv;
        }
#pragma unroll
        for (int jb = 0; jb < 8; ++jb) {
          float beta = 0.0f;
#pragma unroll
          for (int u = 0; u < k - 1; ++u) beta = fmaf(xsS[u], GrowS[u][jb], beta);
          cur[jb] = hb[jb] - beta;
        }
      }
      // masked |.| argmax, first-index tie-break (numpy argmax semantics).
      // u32 compare on fabs bit patterns == f32 compare (non-negative values).
      unsigned curb[8];
      unsigned mv = 0u;
#pragma unroll
      for (int jb = 0; jb < 8; ++jb) {
        float v = ((selmask >> jb) & 1u) ? 0.0f : fabsf(cur[jb]);
        curb[jb] = __float_as_uint(v);
        mv = curb[jb] > mv ? curb[jb] : mv;
      }
      const unsigned M = wave_redmax_u32(mv);
      unsigned cand = 0x7fffffffu;
#pragma unroll
      for (int jb = 7; jb >= 0; --jb)          // descending: final = smallest idx
        cand = (curb[jb] == M) ? (unsigned)(lane + 64 * jb) : cand;
      const int nsel = (int)wave_redmin_u32(cand);
      I[k - 1] = nsel;
      if ((nsel & 63) == lane) selmask |= (1u << (nsel >> 6));
      const int jbn = nsel >> 6, lnn = nsel & 63;   // wave-uniform

      // prefetch G row nsel now; consumed only after the solves (latency hidden)
      float nr[8];
      if constexpr (k <= 4) {
#pragma unroll
        for (int jb = 0; jb < 8; ++jb) nr[jb] = Gm[(size_t)nsel * N_ATOMS + lane + 64 * jb];
      }

      if constexpr (k > 1) {
        // Gs[t] = G[I[t]][nsel] == G[srtI[u]][nsel] from register-cached rows
        float rowval[k - 1];
#pragma unroll
        for (int u = 0; u < k - 1; ++u) {
          float x = GrowS[u][0];
#pragma unroll
          for (int jb = 1; jb < 8; ++jb) x = (jbn == jb) ? GrowS[u][jb] : x;
          rowval[u] = __uint_as_float(
              (unsigned)__builtin_amdgcn_readlane(__float_as_int(x), lnn));
        }
        float Gs[k - 1], w[k - 1];
#pragma unroll
        for (int t = 0; t < k - 1; ++t) {
          float g = 0.0f;
#pragma unroll
          for (int u = 0; u < k - 1; ++u) g = (srtI[u] == I[t]) ? rowval[u] : g;
          Gs[t] = g;
        }
#pragma unroll
        for (int t = 0; t < k - 1; ++t) {
          float a = Gs[t];
#pragma unroll
          for (int u = 0; u < t; ++u) a = a - Lm[t][u] * w[u];
          w[t] = a / Lm[t][t];
        }
        float ss = 0.0f;
#pragma unroll
        for (int t = 0; t < k - 1; ++t) { float sq = w[t] * w[t]; ss = ss + sq; }
        float wc = sqrtf(1.0f - ss);
#pragma unroll
        for (int t = 0; t < k - 1; ++t) Lm[k - 1][t] = w[t];
        Lm[k - 1][k - 1] = wc;
      } else {
        Lm[0][0] = 1.0f;
      }
      // h_bar[nsel] via readlane from hb registers
      float hsel;
      {
        float x = hb[0];
#pragma unroll
        for (int jb = 1; jb < 8; ++jb) x = (jbn == jb) ? hb[jb] : x;
        hsel = __uint_as_float(
            (unsigned)__builtin_amdgcn_readlane(__float_as_int(x), lnn));
      }
      // forward solve: y[0..k-2] bit-identical to previous iteration
      {
        float a = hsel;
#pragma unroll
        for (int u = 0; u < k - 1; ++u) a = a - Lm[k - 1][u] * yv[u];
        yv[k - 1] = a / Lm[k - 1][k - 1];
      }
#pragma unroll
      for (int t = k - 1; t >= 0; --t) {
        float a = yv[t];
#pragma unroll
        for (int u = t + 1; u < k; ++u) a = a - Lm[u][t] * xs[u];
        xs[t] = a / Lm[t][t];
      }
      if constexpr (k <= 4) {
        // insert row nsel (nr) into sorted-by-atom-id register cache
        int p = 0;
#pragma unroll
        for (int u = 0; u < k - 1; ++u) p += (srtI[u] < nsel) ? 1 : 0;
#pragma unroll
        for (int u = k - 1; u >= 1; --u) {
          bool tp = (u > p);
          srtI[u] = tp ? srtI[u - 1] : srtI[u];
#pragma unroll
          for (int jb = 0; jb < 8; ++jb) GrowS[u][jb] = tp ? GrowS[u - 1][jb] : GrowS[u][jb];
        }
#pragma unroll
        for (int u = 0; u < k; ++u) {
          bool at = (u == p);
          srtI[u] = at ? nsel : srtI[u];
#pragma unroll
          for (int jb = 0; jb < 8; ++jb) GrowS[u][jb] = at ? nr[jb] : GrowS[u][jb];
        }
      }
    };
    iter(std::integral_constant<int, 1>{});
    iter(std::integral_constant<int, 2>{});
    iter(std::integral_constant<int, 3>{});
    iter(std::integral_constant<int, 4>{});
    iter(std::integral_constant<int, 5>{});

    if (lane == 0) {
#pragma unroll
      for (int t = 0; t < K_SP; ++t) { IldsI[sl][t] = I[t]; IldsX[sl][t] = xs[t]; }
    }

    // recon in sorted-index order (numpy GEMM sums j ascending)
    int sI[5]; float sX[5];
#pragma unroll
    for (int t = 0; t < 5; ++t) { sI[t] = I[t]; sX[t] = xs[t]; }
#pragma unroll
    for (int a = 0; a < 4; ++a)
#pragma unroll
      for (int t = 0; t < 4 - a; ++t) {
        bool sw = sI[t] > sI[t + 1];
        int   i0 = sw ? sI[t + 1] : sI[t];
        int   i1 = sw ? sI[t] : sI[t + 1];
        float x0 = sw ? sX[t + 1] : sX[t];
        float x1 = sw ? sX[t] : sX[t + 1];
        sI[t] = i0; sI[t + 1] = i1; sX[t] = x0; sX[t + 1] = x1;
      }
    float r = 0.0f;
#pragma unroll
    for (int t = 0; t < 5; ++t) r = fmaf(sX[t], dnT[(size_t)sI[t] * C_DIM + lane], r);
    float ze = Xs[sl][lane];                    // lane-consecutive, conflict-free
    float t1 = r - ze;                          // z_dl - z_e (rounded, as reference)
    out0[(size_t)b * 65536 + lane * 1024 + hw0 + sl] = ze + t1;   // z_dl_st
    float sq = t1 * t1;
    lsum += (double)sq;
  }

  // wave loss reduce + one atomic per wave
#pragma unroll
  for (int m = 1; m < 64; m <<= 1) lsum += __shfl_xor(lsum, m, 64);
  if (lane == 0) atomicAdd(lossAcc, lsum);

  // ---- Phase 3: coeffs zero + scatter for this block's 16 columns ----
  __syncthreads();   // also orders all waves' loss atomics before the counter bump
  {
    int rbase = tid >> 2;
    int c0 = (tid & 3) * 4;
#pragma unroll
    for (int p = 0; p < 8; ++p) {
      int rown = p * 64 + rbase;
      float v[4];
#pragma unroll
      for (int u = 0; u < 4; ++u) {
        int slc = c0 + u;
        float val = 0.0f;
#pragma unroll
        for (int t = 0; t < K_SP; ++t)
          val = (IldsI[slc][t] == rown) ? IldsX[slc][t] : val;
        v[u] = val;
      }
      *reinterpret_cast<float4*>(&coeffs[(size_t)rown * 65536 + sbase + c0]) =
          make_float4(v[0], v[1], v[2], v[3]);
    }
  }

  // last-finishing block writes the final loss (replaces a 4th kernel launch)
  if (tid == 0) {
    __threadfence();
    unsigned int old = atomicAdd(cnt, 1u);
    if (old == (unsigned int)(gridDim.x - 1)) {
      __threadfence();
      double tot = atomicAdd(lossAcc, 0.0);   // atomic read (coherent)
      float dl = (float)(tot / 4194304.0);
      out0[4194304] = dl + 0.25f * dl;
    }
  }
}

extern "C" void kernel_launch(void* const* d_in, const int* in_sizes, int n_in,
                              void* d_out, int out_size, void* d_ws, size_t ws_size,
                              hipStream_t stream) {
  (void)in_sizes; (void)n_in; (void)out_size; (void)ws_size;
  const float* z    = (const float*)d_in[0];   // (64,64,32,32)
  const float* dict = (const float*)d_in[1];   // (64,512)
  float* out    = (float*)d_out;               // z_dl_st | loss | coeffs
  float* coeffs = out + 4194305;
  float* dn  = (float*)d_ws;
  float* dnT = dn + 32768;
  float* G   = dnT + 32768;
  double* lossAcc = (double*)((char*)d_ws + 1310720);
  unsigned int* cnt = (unsigned int*)((char*)d_ws + 1310728);

  prep_norm_k<<<8, 64, 0, stream>>>(dict, dn, dnT, lossAcc, cnt);
  prep_gram_k<<<64, 256, 0, stream>>>(dn, G);
  omp_main_k<<<4096, 256, 0, stream>>>(z, dn, dnT, G, out, coeffs, lossAcc, cnt);
}

// Round 6
// 484.361 us; speedup vs baseline: 1.9526x; 1.9526x over previous
//
#include <hip/hip_runtime.h>
#include <type_traits>

// Problem constants
#define N_ATOMS 512
#define C_DIM   64
#define K_SP    5
#define TS      16      // signals per block
#define HSTR    20      // H LDS row stride in floats (16 + 4 pad, keeps float4 align)

// ws layout (floats):
//   dn   [0,      32768)   : (64 x 512) row-major [c][n]
//   dnT  [32768,  65536)   : (512 x 64) [n][c]
//   G    [65536, 327680)   : (512 x 512)
//   lossAcc (double) at byte offset 327680*4 = 1310720

// This round = EXACT round-2 kernel (best measured: omp_main 373us, total 486)
// + ONE bit-exact trim: y-solve caching (y[0..k-2] are bit-identical across
// OMP iterations because L grows by appending a row; compute only y[k-1]).
// Rationale: rounds 3-5 each bundled changes and each regressed (530/588/850);
// r5's readlane-with-VGPR-index caused waterfall+scratch (WRITE_SIZE 1.3GB).
// Re-anchor at the known-good structure; bisect from here.

// ---------------------------------------------------------------------------
// Kernel 1: column norms + normalized dictionary (dn) + its transpose (dnT).
// ---------------------------------------------------------------------------
__global__ __launch_bounds__(256) void prep_norm_k(const float* __restrict__ dict,
                                                   float* __restrict__ dn,
                                                   float* __restrict__ dnT,
                                                   double* __restrict__ lossAcc) {
#pragma clang fp contract(off)
  const int n = blockIdx.x * 256 + threadIdx.x;
  if (blockIdx.x == 0 && threadIdx.x == 0) *lossAcc = 0.0;
  if (n >= N_ATOMS) return;
  float s = 0.0f;
  for (int c = 0; c < C_DIM; ++c) {
    float v = dict[c * N_ATOMS + n];
    float sq = v * v;
    s = s + sq;
  }
  float m = fmaxf(sqrtf(s), 1e-10f);
  for (int c = 0; c < C_DIM; ++c) {
    float q = dict[c * N_ATOMS + n] / m;
    dn[c * N_ATOMS + n] = q;
    dnT[n * C_DIM + c] = q;
  }
}

// ---------------------------------------------------------------------------
// Kernel 2: G = dn^T dn (512x512), f32 FMA chain sequential over c (BLAS-like
// k-ascending single-accumulator order).
// ---------------------------------------------------------------------------
__global__ __launch_bounds__(256) void prep_gram_k(const float* __restrict__ dn,
                                                   float* __restrict__ G) {
#pragma clang fp contract(off)
  __shared__ float As[64][64];
  __shared__ float Bs[64][64];
  const int bi = blockIdx.x & 7, bj = blockIdx.x >> 3;
  const int tid = threadIdx.x;
  for (int r = 0; r < 16; ++r) {
    int e = r * 256 + tid;
    int c = e >> 6, i = e & 63;
    As[c][i] = dn[c * N_ATOMS + bi * 64 + i];
    Bs[c][i] = dn[c * N_ATOMS + bj * 64 + i];
  }
  __syncthreads();
  const int ti = tid & 15, tj = tid >> 4;
  float acc[4][4] = {};
  for (int c = 0; c < 64; ++c) {
    float a[4], b[4];
#pragma unroll
    for (int u = 0; u < 4; ++u) { a[u] = As[c][ti * 4 + u]; b[u] = Bs[c][tj * 4 + u]; }
#pragma unroll
    for (int u = 0; u < 4; ++u)
#pragma unroll
      for (int v = 0; v < 4; ++v) acc[u][v] = fmaf(a[u], b[v], acc[u][v]);
  }
  for (int u = 0; u < 4; ++u)
    for (int v = 0; v < 4; ++v)
      G[(size_t)(bi * 64 + ti * 4 + u) * N_ATOMS + bj * 64 + tj * 4 + v] = acc[u][v];
}

// ---------------------------------------------------------------------------
// Kernel 3: fused h_bar GEMM + batched OMP + outputs.
// Block = 16 signals (same b, 16 consecutive hw). 256 threads = 4 waves.
// Phase 1: H[512][16] = dn^T * X  (register-blocked, dn chunk-staged in LDS)
// Phase 2: per-wave OMP, 4 signals each (lane = atoms {lane + 64*jb})
// Phase 3: coeffs zero+scatter for the block's 16 columns.
// ---------------------------------------------------------------------------
__global__ __launch_bounds__(256) void omp_main_k(const float* __restrict__ z,
                                                  const float* __restrict__ dn,
                                                  const float* __restrict__ dnT,
                                                  const float* __restrict__ Gm,
                                                  float* __restrict__ out0,
                                                  float* __restrict__ coeffs,
                                                  double* __restrict__ lossAcc) {
#pragma clang fp contract(off)
  __shared__ float Xs[64][16];                       // 4 KB  : Xs[c][sl]
  __shared__ __align__(16) float UB[N_ATOMS * HSTR]; // 40 KB : DnChunk then H
  __shared__ int   IldsI[TS][K_SP];
  __shared__ float IldsX[TS][K_SP];

  const int tid   = threadIdx.x;
  const int sbase = blockIdx.x * TS;
  const int b     = sbase >> 10;
  const int hw0   = sbase & 1023;
  const float* zb = z + (size_t)b * 65536;

  // ---- stage Xs (coalesced float4) ----
  {
    int c = tid >> 2, slc = (tid & 3) * 4;
    float4 v = *reinterpret_cast<const float4*>(zb + c * 1024 + hw0 + slc);
    *reinterpret_cast<float4*>(&Xs[c][slc]) = v;
  }

  // ---- Phase 1: GEMM. thread: atoms {4*ia+r, 256+4*ia+r}, signals {4*js+u}
  const int ia4 = (tid & 63) * 4;
  const int js4 = (tid >> 6) * 4;
  float acc[8][4] = {};
#pragma unroll
  for (int cc = 0; cc < 4; ++cc) {
    __syncthreads();
    {
      const float* src = dn + cc * 8192;   // 16 rows x 512
#pragma unroll
      for (int r = 0; r < 8; ++r) {
        int off = (r * 256 + tid) * 4;
        *reinterpret_cast<float4*>(&UB[off]) = *reinterpret_cast<const float4*>(src + off);
      }
    }
    __syncthreads();
#pragma unroll
    for (int c = 0; c < 16; ++c) {
      const float4 xv = *reinterpret_cast<const float4*>(&Xs[cc * 16 + c][js4]);
      const float4 d0 = *reinterpret_cast<const float4*>(&UB[c * 512 + ia4]);
      const float4 d1 = *reinterpret_cast<const float4*>(&UB[c * 512 + 256 + ia4]);
      const float dv[8] = { d0.x, d0.y, d0.z, d0.w, d1.x, d1.y, d1.z, d1.w };
      const float xw[4] = { xv.x, xv.y, xv.z, xv.w };
#pragma unroll
      for (int r = 0; r < 8; ++r)
#pragma unroll
        for (int u = 0; u < 4; ++u)
          acc[r][u] = fmaf(dv[r], xw[u], acc[r][u]);   // sequential over global c
    }
  }
  __syncthreads();
  // write H into UB (reinterpreted as [512][HSTR])
#pragma unroll
  for (int r = 0; r < 8; ++r) {
    int n = (r < 4) ? (ia4 + r) : (256 + ia4 + (r - 4));
    *reinterpret_cast<float4*>(&UB[n * HSTR + js4]) =
        make_float4(acc[r][0], acc[r][1], acc[r][2], acc[r][3]);
  }
  __syncthreads();

  // ---- Phase 2: OMP (wave per signal, 4 signals per wave) ----
  const int lane = tid & 63;
  const int wid  = tid >> 6;
  double lsum = 0.0;

  for (int q = 0; q < 4; ++q) {
    const int sl = wid * 4 + q;
    float hb[8];
#pragma unroll
    for (int jb = 0; jb < 8; ++jb) hb[jb] = UB[(lane + 64 * jb) * HSTR + sl];

    unsigned selmask = 0;
    int   I[K_SP];
    float xs[K_SP];
    float yv[K_SP];
    float Lm[K_SP][K_SP];
    int   srtI[4];
    float GrowS[4][8];

    auto iter = [&](auto KC) {
      constexpr int k = decltype(KC)::value;
      float cur[8];
      if constexpr (k == 1) {
#pragma unroll
        for (int jb = 0; jb < 8; ++jb) cur[jb] = hb[jb];
      } else {
        // xs values aligned to sorted atom order (numpy sums beta in j-ascending order)
        float xsS[k - 1];
#pragma unroll
        for (int u = 0; u < k - 1; ++u) {
          float xv = 0.0f;
#pragma unroll
          for (int t = 0; t < k - 1; ++t) xv = (I[t] == srtI[u]) ? xs[t] : xv;
          xsS[u] = xv;
        }
#pragma unroll
        for (int jb = 0; jb < 8; ++jb) {
          float beta = 0.0f;
#pragma unroll
          for (int u = 0; u < k - 1; ++u) beta = fmaf(xsS[u], GrowS[u][jb], beta);
          cur[jb] = hb[jb] - beta;
        }
      }
      // masked |.| argmax, first-index tie-break (numpy argmax semantics)
      float bv = -1.0f; int bn = 1 << 30;
#pragma unroll
      for (int jb = 0; jb < 8; ++jb) {
        float v = ((selmask >> jb) & 1u) ? 0.0f : fabsf(cur[jb]);
        int n = lane + 64 * jb;
        bool better = (v > bv) || ((v == bv) && (n < bn));
        bv = better ? v : bv; bn = better ? n : bn;
      }
#pragma unroll
      for (int m = 1; m < 64; m <<= 1) {
        float ov = __shfl_xor(bv, m, 64);
        int   on = __shfl_xor(bn, m, 64);
        bool better = (ov > bv) || ((ov == bv) && (on < bn));
        bv = better ? ov : bv; bn = better ? on : bn;
      }
      const int nsel = bn;
      I[k - 1] = nsel;
      if ((nsel & 63) == lane) selmask |= (1u << (nsel >> 6));

      if constexpr (k > 1) {
        float Gs[k - 1], w[k - 1];
#pragma unroll
        for (int t = 0; t < k - 1; ++t) Gs[t] = Gm[(size_t)I[t] * N_ATOMS + nsel];
#pragma unroll
        for (int t = 0; t < k - 1; ++t) {
          float a = Gs[t];
#pragma unroll
          for (int u = 0; u < t; ++u) a = a - Lm[t][u] * w[u];
          w[t] = a / Lm[t][t];
        }
        float ss = 0.0f;
#pragma unroll
        for (int t = 0; t < k - 1; ++t) { float sq = w[t] * w[t]; ss = ss + sq; }
        float wc = sqrtf(1.0f - ss);
#pragma unroll
        for (int t = 0; t < k - 1; ++t) Lm[k - 1][t] = w[t];
        Lm[k - 1][k - 1] = wc;
      } else {
        Lm[0][0] = 1.0f;
      }
      // forward solve: y[0..k-2] bit-identical to previous iteration
      // (L grows by appending a row) -> compute only y[k-1].
      {
        float a = UB[nsel * HSTR + sl];
#pragma unroll
        for (int u = 0; u < k - 1; ++u) a = a - Lm[k - 1][u] * yv[u];
        yv[k - 1] = a / Lm[k - 1][k - 1];
      }
#pragma unroll
      for (int t = k - 1; t >= 0; --t) {
        float a = yv[t];
#pragma unroll
        for (int u = t + 1; u < k; ++u) a = a - Lm[u][t] * xs[u];
        xs[t] = a / Lm[t][t];
      }
      if constexpr (k <= 4) {
        // load G row of nsel (coalesced) and insert sorted by atom id
        float nr[8];
#pragma unroll
        for (int jb = 0; jb < 8; ++jb) nr[jb] = Gm[(size_t)nsel * N_ATOMS + lane + 64 * jb];
        int p = 0;
#pragma unroll
        for (int u = 0; u < k - 1; ++u) p += (srtI[u] < nsel) ? 1 : 0;
#pragma unroll
        for (int u = k - 1; u >= 1; --u) {
          bool tp = (u > p);
          srtI[u] = tp ? srtI[u - 1] : srtI[u];
#pragma unroll
          for (int jb = 0; jb < 8; ++jb) GrowS[u][jb] = tp ? GrowS[u - 1][jb] : GrowS[u][jb];
        }
#pragma unroll
        for (int u = 0; u < k; ++u) {
          bool at = (u == p);
          srtI[u] = at ? nsel : srtI[u];
#pragma unroll
          for (int jb = 0; jb < 8; ++jb) GrowS[u][jb] = at ? nr[jb] : GrowS[u][jb];
        }
      }
    };
    iter(std::integral_constant<int, 1>{});
    iter(std::integral_constant<int, 2>{});
    iter(std::integral_constant<int, 3>{});
    iter(std::integral_constant<int, 4>{});
    iter(std::integral_constant<int, 5>{});

    if (lane == 0) {
#pragma unroll
      for (int t = 0; t < K_SP; ++t) { IldsI[sl][t] = I[t]; IldsX[sl][t] = xs[t]; }
    }

    // recon in sorted-index order (numpy GEMM sums j ascending)
    int sI[5]; float sX[5];
#pragma unroll
    for (int t = 0; t < 5; ++t) { sI[t] = I[t]; sX[t] = xs[t]; }
#pragma unroll
    for (int a = 0; a < 4; ++a)
#pragma unroll
      for (int t = 0; t < 4 - a; ++t) {
        bool sw = sI[t] > sI[t + 1];
        int   i0 = sw ? sI[t + 1] : sI[t];
        int   i1 = sw ? sI[t] : sI[t + 1];
        float x0 = sw ? sX[t + 1] : sX[t];
        float x1 = sw ? sX[t] : sX[t + 1];
        sI[t] = i0; sI[t + 1] = i1; sX[t] = x0; sX[t + 1] = x1;
      }
    float r = 0.0f;
#pragma unroll
    for (int t = 0; t < 5; ++t) r = fmaf(sX[t], dnT[(size_t)sI[t] * C_DIM + lane], r);
    float ze = Xs[lane][sl];
    float t1 = r - ze;                          // z_dl - z_e (rounded, as reference)
    out0[(size_t)b * 65536 + lane * 1024 + hw0 + sl] = ze + t1;   // z_dl_st
    float sq = t1 * t1;
    lsum += (double)sq;
  }

  // wave loss reduce + one atomic per wave
#pragma unroll
  for (int m = 1; m < 64; m <<= 1) lsum += __shfl_xor(lsum, m, 64);
  if (lane == 0) atomicAdd(lossAcc, lsum);

  // ---- Phase 3: coeffs zero + scatter for this block's 16 columns ----
  __syncthreads();
  {
    int rbase = tid >> 2;
    int c0 = (tid & 3) * 4;
#pragma unroll
    for (int p = 0; p < 8; ++p) {
      int rown = p * 64 + rbase;
      float v[4];
#pragma unroll
      for (int u = 0; u < 4; ++u) {
        int slc = c0 + u;
        float val = 0.0f;
#pragma unroll
        for (int t = 0; t < K_SP; ++t)
          val = (IldsI[slc][t] == rown) ? IldsX[slc][t] : val;
        v[u] = val;
      }
      size_t base = (size_t)rown * 65536 + sbase + c0;
      coeffs[base + 0] = v[0];
      coeffs[base + 1] = v[1];
      coeffs[base + 2] = v[2];
      coeffs[base + 3] = v[3];
    }
  }
}

// ---------------------------------------------------------------------------
// Kernel 4: finalize loss
// ---------------------------------------------------------------------------
__global__ void finalize_k(const double* __restrict__ lossAcc, float* __restrict__ out) {
  if (threadIdx.x == 0) {
    float dl = (float)(*lossAcc / 4194304.0);
    out[4194304] = dl + 0.25f * dl;
  }
}

extern "C" void kernel_launch(void* const* d_in, const int* in_sizes, int n_in,
                              void* d_out, int out_size, void* d_ws, size_t ws_size,
                              hipStream_t stream) {
  (void)in_sizes; (void)n_in; (void)out_size; (void)ws_size;
  const float* z    = (const float*)d_in[0];   // (64,64,32,32)
  const float* dict = (const float*)d_in[1];   // (64,512)
  float* out    = (float*)d_out;               // z_dl_st | loss | coeffs
  float* coeffs = out + 4194305;
  float* dn  = (float*)d_ws;
  float* dnT = dn + 32768;
  float* G   = dnT + 32768;
  double* lossAcc = (double*)((char*)d_ws + 1310720);

  prep_norm_k<<<2, 256, 0, stream>>>(dict, dn, dnT, lossAcc);
  prep_gram_k<<<64, 256, 0, stream>>>(dn, G);
  omp_main_k<<<4096, 256, 0, stream>>>(z, dn, dnT, G, out, coeffs, lossAcc);
  finalize_k<<<1, 64, 0, stream>>>(lossAcc, out);
}

// Round 7
// 435.576 us; speedup vs baseline: 2.1713x; 1.1120x over previous
//
#include <hip/hip_runtime.h>
#include <type_traits>

// Problem constants
#define N_ATOMS 512
#define C_DIM   64
#define K_SP    5
#define TS      16      // signals per block
#define HSTR    20      // H LDS row stride in floats (16 + 4 pad, keeps float4 align)

// ws layout (floats):
//   dn   [0,      32768)   : (64 x 512) row-major [c][n]
//   dnT  [32768,  65536)   : (512 x 64) [n][c]
//   G    [65536, 327680)   : (512 x 512)
//   lossAcc (double) at byte offset 327680*4 = 1310720

// R7 = r6 anchor + ONE change: DPP argmax (replaces __shfl_xor butterfly).
// Rationale: 8.26M bank conflicts / 4096 blocks ~= the ~960 ds_bpermutes per
// block issued by the butterflies; they also serialize the DS crossbar and sit
// on phase 2's critical path (~400-700cy/argmax). DPP is pure-VALU (~50cy),
// functionally validated in r5 (r5's regression was readlane-waterfall, not DPP).

// ---------------------------------------------------------------------------
// Wave64 DPP reductions. quad_perm(1,0,3,2)=0xB1, quad_perm(2,3,0,1)=0x4E,
// row_half_mirror=0x141, row_mirror=0x140, row_bcast15=0x142, row_bcast31=0x143.
// After the chain lane 63 holds the full-wave result; readlane(63) (constant
// index -> no waterfall) broadcasts it.
// ---------------------------------------------------------------------------
__device__ __forceinline__ unsigned wave_redmax_u32(unsigned u) {
  unsigned t;
  t = (unsigned)__builtin_amdgcn_update_dpp((int)u, (int)u, 0xB1, 0xF, 0xF, false); u = t > u ? t : u;
  t = (unsigned)__builtin_amdgcn_update_dpp((int)u, (int)u, 0x4E, 0xF, 0xF, false); u = t > u ? t : u;
  t = (unsigned)__builtin_amdgcn_update_dpp((int)u, (int)u, 0x141, 0xF, 0xF, false); u = t > u ? t : u;
  t = (unsigned)__builtin_amdgcn_update_dpp((int)u, (int)u, 0x140, 0xF, 0xF, false); u = t > u ? t : u;
  t = (unsigned)__builtin_amdgcn_update_dpp((int)u, (int)u, 0x142, 0xF, 0xF, false); u = t > u ? t : u;
  t = (unsigned)__builtin_amdgcn_update_dpp((int)u, (int)u, 0x143, 0xF, 0xF, false); u = t > u ? t : u;
  return (unsigned)__builtin_amdgcn_readlane((int)u, 63);
}
__device__ __forceinline__ unsigned wave_redmin_u32(unsigned u) {
  unsigned t;
  t = (unsigned)__builtin_amdgcn_update_dpp((int)u, (int)u, 0xB1, 0xF, 0xF, false); u = t < u ? t : u;
  t = (unsigned)__builtin_amdgcn_update_dpp((int)u, (int)u, 0x4E, 0xF, 0xF, false); u = t < u ? t : u;
  t = (unsigned)__builtin_amdgcn_update_dpp((int)u, (int)u, 0x141, 0xF, 0xF, false); u = t < u ? t : u;
  t = (unsigned)__builtin_amdgcn_update_dpp((int)u, (int)u, 0x140, 0xF, 0xF, false); u = t < u ? t : u;
  t = (unsigned)__builtin_amdgcn_update_dpp((int)u, (int)u, 0x142, 0xF, 0xF, false); u = t < u ? t : u;
  t = (unsigned)__builtin_amdgcn_update_dpp((int)u, (int)u, 0x143, 0xF, 0xF, false); u = t < u ? t : u;
  return (unsigned)__builtin_amdgcn_readlane((int)u, 63);
}

// ---------------------------------------------------------------------------
// Kernel 1: column norms + normalized dictionary (dn) + its transpose (dnT).
// ---------------------------------------------------------------------------
__global__ __launch_bounds__(256) void prep_norm_k(const float* __restrict__ dict,
                                                   float* __restrict__ dn,
                                                   float* __restrict__ dnT,
                                                   double* __restrict__ lossAcc) {
#pragma clang fp contract(off)
  const int n = blockIdx.x * 256 + threadIdx.x;
  if (blockIdx.x == 0 && threadIdx.x == 0) *lossAcc = 0.0;
  if (n >= N_ATOMS) return;
  float s = 0.0f;
  for (int c = 0; c < C_DIM; ++c) {
    float v = dict[c * N_ATOMS + n];
    float sq = v * v;
    s = s + sq;
  }
  float m = fmaxf(sqrtf(s), 1e-10f);
  for (int c = 0; c < C_DIM; ++c) {
    float q = dict[c * N_ATOMS + n] / m;
    dn[c * N_ATOMS + n] = q;
    dnT[n * C_DIM + c] = q;
  }
}

// ---------------------------------------------------------------------------
// Kernel 2: G = dn^T dn (512x512), f32 FMA chain sequential over c.
// ---------------------------------------------------------------------------
__global__ __launch_bounds__(256) void prep_gram_k(const float* __restrict__ dn,
                                                   float* __restrict__ G) {
#pragma clang fp contract(off)
  __shared__ float As[64][64];
  __shared__ float Bs[64][64];
  const int bi = blockIdx.x & 7, bj = blockIdx.x >> 3;
  const int tid = threadIdx.x;
  for (int r = 0; r < 16; ++r) {
    int e = r * 256 + tid;
    int c = e >> 6, i = e & 63;
    As[c][i] = dn[c * N_ATOMS + bi * 64 + i];
    Bs[c][i] = dn[c * N_ATOMS + bj * 64 + i];
  }
  __syncthreads();
  const int ti = tid & 15, tj = tid >> 4;
  float acc[4][4] = {};
  for (int c = 0; c < 64; ++c) {
    float a[4], b[4];
#pragma unroll
    for (int u = 0; u < 4; ++u) { a[u] = As[c][ti * 4 + u]; b[u] = Bs[c][tj * 4 + u]; }
#pragma unroll
    for (int u = 0; u < 4; ++u)
#pragma unroll
      for (int v = 0; v < 4; ++v) acc[u][v] = fmaf(a[u], b[v], acc[u][v]);
  }
  for (int u = 0; u < 4; ++u)
    for (int v = 0; v < 4; ++v)
      G[(size_t)(bi * 64 + ti * 4 + u) * N_ATOMS + bj * 64 + tj * 4 + v] = acc[u][v];
}

// ---------------------------------------------------------------------------
// Kernel 3: fused h_bar GEMM + batched OMP + outputs.
// ---------------------------------------------------------------------------
__global__ __launch_bounds__(256) void omp_main_k(const float* __restrict__ z,
                                                  const float* __restrict__ dn,
                                                  const float* __restrict__ dnT,
                                                  const float* __restrict__ Gm,
                                                  float* __restrict__ out0,
                                                  float* __restrict__ coeffs,
                                                  double* __restrict__ lossAcc) {
#pragma clang fp contract(off)
  __shared__ float Xs[64][16];                       // 4 KB  : Xs[c][sl]
  __shared__ __align__(16) float UB[N_ATOMS * HSTR]; // 40 KB : DnChunk then H
  __shared__ int   IldsI[TS][K_SP];
  __shared__ float IldsX[TS][K_SP];

  const int tid   = threadIdx.x;
  const int sbase = blockIdx.x * TS;
  const int b     = sbase >> 10;
  const int hw0   = sbase & 1023;
  const float* zb = z + (size_t)b * 65536;

  // ---- stage Xs (coalesced float4) ----
  {
    int c = tid >> 2, slc = (tid & 3) * 4;
    float4 v = *reinterpret_cast<const float4*>(zb + c * 1024 + hw0 + slc);
    *reinterpret_cast<float4*>(&Xs[c][slc]) = v;
  }

  // ---- Phase 1: GEMM. thread: atoms {4*ia+r, 256+4*ia+r}, signals {4*js+u}
  const int ia4 = (tid & 63) * 4;
  const int js4 = (tid >> 6) * 4;
  float acc[8][4] = {};
#pragma unroll
  for (int cc = 0; cc < 4; ++cc) {
    __syncthreads();
    {
      const float* src = dn + cc * 8192;   // 16 rows x 512
#pragma unroll
      for (int r = 0; r < 8; ++r) {
        int off = (r * 256 + tid) * 4;
        *reinterpret_cast<float4*>(&UB[off]) = *reinterpret_cast<const float4*>(src + off);
      }
    }
    __syncthreads();
#pragma unroll
    for (int c = 0; c < 16; ++c) {
      const float4 xv = *reinterpret_cast<const float4*>(&Xs[cc * 16 + c][js4]);
      const float4 d0 = *reinterpret_cast<const float4*>(&UB[c * 512 + ia4]);
      const float4 d1 = *reinterpret_cast<const float4*>(&UB[c * 512 + 256 + ia4]);
      const float dv[8] = { d0.x, d0.y, d0.z, d0.w, d1.x, d1.y, d1.z, d1.w };
      const float xw[4] = { xv.x, xv.y, xv.z, xv.w };
#pragma unroll
      for (int r = 0; r < 8; ++r)
#pragma unroll
        for (int u = 0; u < 4; ++u)
          acc[r][u] = fmaf(dv[r], xw[u], acc[r][u]);   // sequential over global c
    }
  }
  __syncthreads();
  // write H into UB (reinterpreted as [512][HSTR])
#pragma unroll
  for (int r = 0; r < 8; ++r) {
    int n = (r < 4) ? (ia4 + r) : (256 + ia4 + (r - 4));
    *reinterpret_cast<float4*>(&UB[n * HSTR + js4]) =
        make_float4(acc[r][0], acc[r][1], acc[r][2], acc[r][3]);
  }
  __syncthreads();

  // ---- Phase 2: OMP (wave per signal, 4 signals per wave) ----
  const int lane = tid & 63;
  const int wid  = tid >> 6;
  double lsum = 0.0;

  for (int q = 0; q < 4; ++q) {
    const int sl = wid * 4 + q;
    float hb[8];
#pragma unroll
    for (int jb = 0; jb < 8; ++jb) hb[jb] = UB[(lane + 64 * jb) * HSTR + sl];

    unsigned selmask = 0;
    int   I[K_SP];
    float xs[K_SP];
    float yv[K_SP];
    float Lm[K_SP][K_SP];
    int   srtI[4];
    float GrowS[4][8];

    auto iter = [&](auto KC) {
      constexpr int k = decltype(KC)::value;
      float cur[8];
      if constexpr (k == 1) {
#pragma unroll
        for (int jb = 0; jb < 8; ++jb) cur[jb] = hb[jb];
      } else {
        // xs values aligned to sorted atom order (numpy sums beta j-ascending)
        float xsS[k - 1];
#pragma unroll
        for (int u = 0; u < k - 1; ++u) {
          float xv = 0.0f;
#pragma unroll
          for (int t = 0; t < k - 1; ++t) xv = (I[t] == srtI[u]) ? xs[t] : xv;
          xsS[u] = xv;
        }
#pragma unroll
        for (int jb = 0; jb < 8; ++jb) {
          float beta = 0.0f;
#pragma unroll
          for (int u = 0; u < k - 1; ++u) beta = fmaf(xsS[u], GrowS[u][jb], beta);
          cur[jb] = hb[jb] - beta;
        }
      }
      // masked |.| argmax, first-index tie-break (numpy argmax semantics).
      // u32 compare on fabs bit patterns == f32 compare (non-negative values).
      unsigned curb[8];
      unsigned mv = 0u;
#pragma unroll
      for (int jb = 0; jb < 8; ++jb) {
        float v = ((selmask >> jb) & 1u) ? 0.0f : fabsf(cur[jb]);
        curb[jb] = __float_as_uint(v);
        mv = curb[jb] > mv ? curb[jb] : mv;
      }
      const unsigned M = wave_redmax_u32(mv);
      unsigned cand = 0x7fffffffu;
#pragma unroll
      for (int jb = 7; jb >= 0; --jb)          // descending: final = smallest idx
        cand = (curb[jb] == M) ? (unsigned)(lane + 64 * jb) : cand;
      const int nsel = (int)wave_redmin_u32(cand);
      I[k - 1] = nsel;
      if ((nsel & 63) == lane) selmask |= (1u << (nsel >> 6));

      if constexpr (k > 1) {
        float Gs[k - 1], w[k - 1];
#pragma unroll
        for (int t = 0; t < k - 1; ++t) Gs[t] = Gm[(size_t)I[t] * N_ATOMS + nsel];
#pragma unroll
        for (int t = 0; t < k - 1; ++t) {
          float a = Gs[t];
#pragma unroll
          for (int u = 0; u < t; ++u) a = a - Lm[t][u] * w[u];
          w[t] = a / Lm[t][t];
        }
        float ss = 0.0f;
#pragma unroll
        for (int t = 0; t < k - 1; ++t) { float sq = w[t] * w[t]; ss = ss + sq; }
        float wc = sqrtf(1.0f - ss);
#pragma unroll
        for (int t = 0; t < k - 1; ++t) Lm[k - 1][t] = w[t];
        Lm[k - 1][k - 1] = wc;
      } else {
        Lm[0][0] = 1.0f;
      }
      // forward solve: y[0..k-2] bit-identical to previous iteration
      // (L grows by appending a row) -> compute only y[k-1].
      {
        float a = UB[nsel * HSTR + sl];
#pragma unroll
        for (int u = 0; u < k - 1; ++u) a = a - Lm[k - 1][u] * yv[u];
        yv[k - 1] = a / Lm[k - 1][k - 1];
      }
#pragma unroll
      for (int t = k - 1; t >= 0; --t) {
        float a = yv[t];
#pragma unroll
        for (int u = t + 1; u < k; ++u) a = a - Lm[u][t] * xs[u];
        xs[t] = a / Lm[t][t];
      }
      if constexpr (k <= 4) {
        // load G row of nsel (coalesced) and insert sorted by atom id
        float nr[8];
#pragma unroll
        for (int jb = 0; jb < 8; ++jb) nr[jb] = Gm[(size_t)nsel * N_ATOMS + lane + 64 * jb];
        int p = 0;
#pragma unroll
        for (int u = 0; u < k - 1; ++u) p += (srtI[u] < nsel) ? 1 : 0;
#pragma unroll
        for (int u = k - 1; u >= 1; --u) {
          bool tp = (u > p);
          srtI[u] = tp ? srtI[u - 1] : srtI[u];
#pragma unroll
          for (int jb = 0; jb < 8; ++jb) GrowS[u][jb] = tp ? GrowS[u - 1][jb] : GrowS[u][jb];
        }
#pragma unroll
        for (int u = 0; u < k; ++u) {
          bool at = (u == p);
          srtI[u] = at ? nsel : srtI[u];
#pragma unroll
          for (int jb = 0; jb < 8; ++jb) GrowS[u][jb] = at ? nr[jb] : GrowS[u][jb];
        }
      }
    };
    iter(std::integral_constant<int, 1>{});
    iter(std::integral_constant<int, 2>{});
    iter(std::integral_constant<int, 3>{});
    iter(std::integral_constant<int, 4>{});
    iter(std::integral_constant<int, 5>{});

    if (lane == 0) {
#pragma unroll
      for (int t = 0; t < K_SP; ++t) { IldsI[sl][t] = I[t]; IldsX[sl][t] = xs[t]; }
    }

    // recon in sorted-index order (numpy GEMM sums j ascending)
    int sI[5]; float sX[5];
#pragma unroll
    for (int t = 0; t < 5; ++t) { sI[t] = I[t]; sX[t] = xs[t]; }
#pragma unroll
    for (int a = 0; a < 4; ++a)
#pragma unroll
      for (int t = 0; t < 4 - a; ++t) {
        bool sw = sI[t] > sI[t + 1];
        int   i0 = sw ? sI[t + 1] : sI[t];
        int   i1 = sw ? sI[t] : sI[t + 1];
        float x0 = sw ? sX[t + 1] : sX[t];
        float x1 = sw ? sX[t] : sX[t + 1];
        sI[t] = i0; sI[t + 1] = i1; sX[t] = x0; sX[t + 1] = x1;
      }
    float r = 0.0f;
#pragma unroll
    for (int t = 0; t < 5; ++t) r = fmaf(sX[t], dnT[(size_t)sI[t] * C_DIM + lane], r);
    float ze = Xs[lane][sl];
    float t1 = r - ze;                          // z_dl - z_e (rounded, as reference)
    out0[(size_t)b * 65536 + lane * 1024 + hw0 + sl] = ze + t1;   // z_dl_st
    float sq = t1 * t1;
    lsum += (double)sq;
  }

  // wave loss reduce + one atomic per wave
#pragma unroll
  for (int m = 1; m < 64; m <<= 1) lsum += __shfl_xor(lsum, m, 64);
  if (lane == 0) atomicAdd(lossAcc, lsum);

  // ---- Phase 3: coeffs zero + scatter for this block's 16 columns ----
  __syncthreads();
  {
    int rbase = tid >> 2;
    int c0 = (tid & 3) * 4;
#pragma unroll
    for (int p = 0; p < 8; ++p) {
      int rown = p * 64 + rbase;
      float v[4];
#pragma unroll
      for (int u = 0; u < 4; ++u) {
        int slc = c0 + u;
        float val = 0.0f;
#pragma unroll
        for (int t = 0; t < K_SP; ++t)
          val = (IldsI[slc][t] == rown) ? IldsX[slc][t] : val;
        v[u] = val;
      }
      size_t base = (size_t)rown * 65536 + sbase + c0;
      coeffs[base + 0] = v[0];
      coeffs[base + 1] = v[1];
      coeffs[base + 2] = v[2];
      coeffs[base + 3] = v[3];
    }
  }
}

// ---------------------------------------------------------------------------
// Kernel 4: finalize loss
// ---------------------------------------------------------------------------
__global__ void finalize_k(const double* __restrict__ lossAcc, float* __restrict__ out) {
  if (threadIdx.x == 0) {
    float dl = (float)(*lossAcc / 4194304.0);
    out[4194304] = dl + 0.25f * dl;
  }
}

extern "C" void kernel_launch(void* const* d_in, const int* in_sizes, int n_in,
                              void* d_out, int out_size, void* d_ws, size_t ws_size,
                              hipStream_t stream) {
  (void)in_sizes; (void)n_in; (void)out_size; (void)ws_size;
  const float* z    = (const float*)d_in[0];   // (64,64,32,32)
  const float* dict = (const float*)d_in[1];   // (64,512)
  float* out    = (float*)d_out;               // z_dl_st | loss | coeffs
  float* coeffs = out + 4194305;
  float* dn  = (float*)d_ws;
  float* dnT = dn + 32768;
  float* G   = dnT + 32768;
  double* lossAcc = (double*)((char*)d_ws + 1310720);

  prep_norm_k<<<2, 256, 0, stream>>>(dict, dn, dnT, lossAcc);
  prep_gram_k<<<64, 256, 0, stream>>>(dn, G);
  omp_main_k<<<4096, 256, 0, stream>>>(z, dn, dnT, G, out, coeffs, lossAcc);
  finalize_k<<<1, 64, 0, stream>>>(lossAcc, out);
}

// Round 8
// 433.100 us; speedup vs baseline: 2.1837x; 1.0057x over previous
//
#include <hip/hip_runtime.h>
#include <type_traits>

// Problem constants
#define N_ATOMS 512
#define C_DIM   64
#define K_SP    5
#define TS      16      // signals per block
#define HROW    512     // H row stride: H stored [sl][atom], unioned with dn chunk

// ws layout (floats):
//   dn   [0,      32768)   : (64 x 512) row-major [c][n]
//   dnT  [32768,  65536)   : (512 x 64) [n][c]
//   G    [65536, 327680)   : (512 x 512)
//   lossAcc (double) at byte offset 327680*4 = 1310720

// R8 = r7 anchor + ONE change: H layout transposed to UB[16][512].
// hb reads lane-consecutive (conflict-free), H writes dense float4
// (conflict-free), UB 40KB -> 32KB => LDS 46080 -> ~37.5KB => 4 blocks/CU
// (16 waves/CU, +33% TLP for the latency-bound OMP chain).
// r7 evidence: conflicts(8.26M) = HSTR=20 strided H accesses; occupancy 22%
// was the binding constraint (LDS-capped 3 blocks/CU).

// ---------------------------------------------------------------------------
// Wave64 DPP reductions (pure VALU, ~50cy; r7 win: argmax 412->320us).
// ---------------------------------------------------------------------------
__device__ __forceinline__ unsigned wave_redmax_u32(unsigned u) {
  unsigned t;
  t = (unsigned)__builtin_amdgcn_update_dpp((int)u, (int)u, 0xB1, 0xF, 0xF, false); u = t > u ? t : u;
  t = (unsigned)__builtin_amdgcn_update_dpp((int)u, (int)u, 0x4E, 0xF, 0xF, false); u = t > u ? t : u;
  t = (unsigned)__builtin_amdgcn_update_dpp((int)u, (int)u, 0x141, 0xF, 0xF, false); u = t > u ? t : u;
  t = (unsigned)__builtin_amdgcn_update_dpp((int)u, (int)u, 0x140, 0xF, 0xF, false); u = t > u ? t : u;
  t = (unsigned)__builtin_amdgcn_update_dpp((int)u, (int)u, 0x142, 0xF, 0xF, false); u = t > u ? t : u;
  t = (unsigned)__builtin_amdgcn_update_dpp((int)u, (int)u, 0x143, 0xF, 0xF, false); u = t > u ? t : u;
  return (unsigned)__builtin_amdgcn_readlane((int)u, 63);
}
__device__ __forceinline__ unsigned wave_redmin_u32(unsigned u) {
  unsigned t;
  t = (unsigned)__builtin_amdgcn_update_dpp((int)u, (int)u, 0xB1, 0xF, 0xF, false); u = t < u ? t : u;
  t = (unsigned)__builtin_amdgcn_update_dpp((int)u, (int)u, 0x4E, 0xF, 0xF, false); u = t < u ? t : u;
  t = (unsigned)__builtin_amdgcn_update_dpp((int)u, (int)u, 0x141, 0xF, 0xF, false); u = t < u ? t : u;
  t = (unsigned)__builtin_amdgcn_update_dpp((int)u, (int)u, 0x140, 0xF, 0xF, false); u = t < u ? t : u;
  t = (unsigned)__builtin_amdgcn_update_dpp((int)u, (int)u, 0x142, 0xF, 0xF, false); u = t < u ? t : u;
  t = (unsigned)__builtin_amdgcn_update_dpp((int)u, (int)u, 0x143, 0xF, 0xF, false); u = t < u ? t : u;
  return (unsigned)__builtin_amdgcn_readlane((int)u, 63);
}

// ---------------------------------------------------------------------------
// Kernel 1: column norms + normalized dictionary (dn) + its transpose (dnT).
// ---------------------------------------------------------------------------
__global__ __launch_bounds__(256) void prep_norm_k(const float* __restrict__ dict,
                                                   float* __restrict__ dn,
                                                   float* __restrict__ dnT,
                                                   double* __restrict__ lossAcc) {
#pragma clang fp contract(off)
  const int n = blockIdx.x * 256 + threadIdx.x;
  if (blockIdx.x == 0 && threadIdx.x == 0) *lossAcc = 0.0;
  if (n >= N_ATOMS) return;
  float s = 0.0f;
  for (int c = 0; c < C_DIM; ++c) {
    float v = dict[c * N_ATOMS + n];
    float sq = v * v;
    s = s + sq;
  }
  float m = fmaxf(sqrtf(s), 1e-10f);
  for (int c = 0; c < C_DIM; ++c) {
    float q = dict[c * N_ATOMS + n] / m;
    dn[c * N_ATOMS + n] = q;
    dnT[n * C_DIM + c] = q;
  }
}

// ---------------------------------------------------------------------------
// Kernel 2: G = dn^T dn (512x512), f32 FMA chain sequential over c.
// ---------------------------------------------------------------------------
__global__ __launch_bounds__(256) void prep_gram_k(const float* __restrict__ dn,
                                                   float* __restrict__ G) {
#pragma clang fp contract(off)
  __shared__ float As[64][64];
  __shared__ float Bs[64][64];
  const int bi = blockIdx.x & 7, bj = blockIdx.x >> 3;
  const int tid = threadIdx.x;
  for (int r = 0; r < 16; ++r) {
    int e = r * 256 + tid;
    int c = e >> 6, i = e & 63;
    As[c][i] = dn[c * N_ATOMS + bi * 64 + i];
    Bs[c][i] = dn[c * N_ATOMS + bj * 64 + i];
  }
  __syncthreads();
  const int ti = tid & 15, tj = tid >> 4;
  float acc[4][4] = {};
  for (int c = 0; c < 64; ++c) {
    float a[4], b[4];
#pragma unroll
    for (int u = 0; u < 4; ++u) { a[u] = As[c][ti * 4 + u]; b[u] = Bs[c][tj * 4 + u]; }
#pragma unroll
    for (int u = 0; u < 4; ++u)
#pragma unroll
      for (int v = 0; v < 4; ++v) acc[u][v] = fmaf(a[u], b[v], acc[u][v]);
  }
  for (int u = 0; u < 4; ++u)
    for (int v = 0; v < 4; ++v)
      G[(size_t)(bi * 64 + ti * 4 + u) * N_ATOMS + bj * 64 + tj * 4 + v] = acc[u][v];
}

// ---------------------------------------------------------------------------
// Kernel 3: fused h_bar GEMM + batched OMP + outputs.
// ---------------------------------------------------------------------------
__global__ __launch_bounds__(256) void omp_main_k(const float* __restrict__ z,
                                                  const float* __restrict__ dn,
                                                  const float* __restrict__ dnT,
                                                  const float* __restrict__ Gm,
                                                  float* __restrict__ out0,
                                                  float* __restrict__ coeffs,
                                                  double* __restrict__ lossAcc) {
#pragma clang fp contract(off)
  __shared__ float Xs[64][16];                       // 4 KB  : Xs[c][sl]
  __shared__ __align__(16) float UB[TS * HROW];      // 32 KB : dn chunk, then H[sl][atom]
  __shared__ int   IldsI[TS][K_SP];
  __shared__ float IldsX[TS][K_SP];

  const int tid   = threadIdx.x;
  const int sbase = blockIdx.x * TS;
  const int b     = sbase >> 10;
  const int hw0   = sbase & 1023;
  const float* zb = z + (size_t)b * 65536;

  // ---- stage Xs (coalesced float4) ----
  {
    int c = tid >> 2, slc = (tid & 3) * 4;
    float4 v = *reinterpret_cast<const float4*>(zb + c * 1024 + hw0 + slc);
    *reinterpret_cast<float4*>(&Xs[c][slc]) = v;
  }

  // ---- Phase 1: GEMM. thread: atoms {4*ia+r, 256+4*ia+r}, signals {4*js+u}
  const int ia4 = (tid & 63) * 4;
  const int js4 = (tid >> 6) * 4;
  float acc[8][4] = {};
#pragma unroll
  for (int cc = 0; cc < 4; ++cc) {
    __syncthreads();
    {
      const float* src = dn + cc * 8192;   // 16 rows x 512
#pragma unroll
      for (int r = 0; r < 8; ++r) {
        int off = (r * 256 + tid) * 4;
        *reinterpret_cast<float4*>(&UB[off]) = *reinterpret_cast<const float4*>(src + off);
      }
    }
    __syncthreads();
#pragma unroll
    for (int c = 0; c < 16; ++c) {
      const float4 xv = *reinterpret_cast<const float4*>(&Xs[cc * 16 + c][js4]);
      const float4 d0 = *reinterpret_cast<const float4*>(&UB[c * 512 + ia4]);
      const float4 d1 = *reinterpret_cast<const float4*>(&UB[c * 512 + 256 + ia4]);
      const float dv[8] = { d0.x, d0.y, d0.z, d0.w, d1.x, d1.y, d1.z, d1.w };
      const float xw[4] = { xv.x, xv.y, xv.z, xv.w };
#pragma unroll
      for (int r = 0; r < 8; ++r)
#pragma unroll
        for (int u = 0; u < 4; ++u)
          acc[r][u] = fmaf(dv[r], xw[u], acc[r][u]);   // sequential over global c
    }
  }
  __syncthreads();
  // write H[sl][atom]: per signal u, dense float4 at lane*4 (conflict-free)
#pragma unroll
  for (int u = 0; u < 4; ++u) {
    const int sl = js4 + u;
    *reinterpret_cast<float4*>(&UB[sl * HROW + ia4]) =
        make_float4(acc[0][u], acc[1][u], acc[2][u], acc[3][u]);
    *reinterpret_cast<float4*>(&UB[sl * HROW + 256 + ia4]) =
        make_float4(acc[4][u], acc[5][u], acc[6][u], acc[7][u]);
  }
  __syncthreads();

  // ---- Phase 2: OMP (wave per signal, 4 signals per wave) ----
  const int lane = tid & 63;
  const int wid  = tid >> 6;
  double lsum = 0.0;

  for (int q = 0; q < 4; ++q) {
    const int sl = wid * 4 + q;
    float hb[8];
#pragma unroll
    for (int jb = 0; jb < 8; ++jb) hb[jb] = UB[sl * HROW + lane + 64 * jb];  // lane-consecutive

    unsigned selmask = 0;
    int   I[K_SP];
    float xs[K_SP];
    float yv[K_SP];
    float Lm[K_SP][K_SP];
    int   srtI[4];
    float GrowS[4][8];

    auto iter = [&](auto KC) {
      constexpr int k = decltype(KC)::value;
      float cur[8];
      if constexpr (k == 1) {
#pragma unroll
        for (int jb = 0; jb < 8; ++jb) cur[jb] = hb[jb];
      } else {
        // xs values aligned to sorted atom order (numpy sums beta j-ascending)
        float xsS[k - 1];
#pragma unroll
        for (int u = 0; u < k - 1; ++u) {
          float xv = 0.0f;
#pragma unroll
          for (int t = 0; t < k - 1; ++t) xv = (I[t] == srtI[u]) ? xs[t] : xv;
          xsS[u] = xv;
        }
#pragma unroll
        for (int jb = 0; jb < 8; ++jb) {
          float beta = 0.0f;
#pragma unroll
          for (int u = 0; u < k - 1; ++u) beta = fmaf(xsS[u], GrowS[u][jb], beta);
          cur[jb] = hb[jb] - beta;
        }
      }
      // masked |.| argmax, first-index tie-break (numpy argmax semantics).
      unsigned curb[8];
      unsigned mv = 0u;
#pragma unroll
      for (int jb = 0; jb < 8; ++jb) {
        float v = ((selmask >> jb) & 1u) ? 0.0f : fabsf(cur[jb]);
        curb[jb] = __float_as_uint(v);
        mv = curb[jb] > mv ? curb[jb] : mv;
      }
      const unsigned M = wave_redmax_u32(mv);
      unsigned cand = 0x7fffffffu;
#pragma unroll
      for (int jb = 7; jb >= 0; --jb)          // descending: final = smallest idx
        cand = (curb[jb] == M) ? (unsigned)(lane + 64 * jb) : cand;
      const int nsel = (int)wave_redmin_u32(cand);
      I[k - 1] = nsel;
      if ((nsel & 63) == lane) selmask |= (1u << (nsel >> 6));

      if constexpr (k > 1) {
        float Gs[k - 1], w[k - 1];
#pragma unroll
        for (int t = 0; t < k - 1; ++t) Gs[t] = Gm[(size_t)I[t] * N_ATOMS + nsel];
#pragma unroll
        for (int t = 0; t < k - 1; ++t) {
          float a = Gs[t];
#pragma unroll
          for (int u = 0; u < t; ++u) a = a - Lm[t][u] * w[u];
          w[t] = a / Lm[t][t];
        }
        float ss = 0.0f;
#pragma unroll
        for (int t = 0; t < k - 1; ++t) { float sq = w[t] * w[t]; ss = ss + sq; }
        float wc = sqrtf(1.0f - ss);
#pragma unroll
        for (int t = 0; t < k - 1; ++t) Lm[k - 1][t] = w[t];
        Lm[k - 1][k - 1] = wc;
      } else {
        Lm[0][0] = 1.0f;
      }
      // forward solve: y[0..k-2] bit-identical to previous iteration
      // (L grows by appending a row) -> compute only y[k-1].
      {
        float a = UB[sl * HROW + nsel];
#pragma unroll
        for (int u = 0; u < k - 1; ++u) a = a - Lm[k - 1][u] * yv[u];
        yv[k - 1] = a / Lm[k - 1][k - 1];
      }
#pragma unroll
      for (int t = k - 1; t >= 0; --t) {
        float a = yv[t];
#pragma unroll
        for (int u = t + 1; u < k; ++u) a = a - Lm[u][t] * xs[u];
        xs[t] = a / Lm[t][t];
      }
      if constexpr (k <= 4) {
        // load G row of nsel (coalesced) and insert sorted by atom id
        float nr[8];
#pragma unroll
        for (int jb = 0; jb < 8; ++jb) nr[jb] = Gm[(size_t)nsel * N_ATOMS + lane + 64 * jb];
        int p = 0;
#pragma unroll
        for (int u = 0; u < k - 1; ++u) p += (srtI[u] < nsel) ? 1 : 0;
#pragma unroll
        for (int u = k - 1; u >= 1; --u) {
          bool tp = (u > p);
          srtI[u] = tp ? srtI[u - 1] : srtI[u];
#pragma unroll
          for (int jb = 0; jb < 8; ++jb) GrowS[u][jb] = tp ? GrowS[u - 1][jb] : GrowS[u][jb];
        }
#pragma unroll
        for (int u = 0; u < k; ++u) {
          bool at = (u == p);
          srtI[u] = at ? nsel : srtI[u];
#pragma unroll
          for (int jb = 0; jb < 8; ++jb) GrowS[u][jb] = at ? nr[jb] : GrowS[u][jb];
        }
      }
    };
    iter(std::integral_constant<int, 1>{});
    iter(std::integral_constant<int, 2>{});
    iter(std::integral_constant<int, 3>{});
    iter(std::integral_constant<int, 4>{});
    iter(std::integral_constant<int, 5>{});

    if (lane == 0) {
#pragma unroll
      for (int t = 0; t < K_SP; ++t) { IldsI[sl][t] = I[t]; IldsX[sl][t] = xs[t]; }
    }

    // recon in sorted-index order (numpy GEMM sums j ascending)
    int sI[5]; float sX[5];
#pragma unroll
    for (int t = 0; t < 5; ++t) { sI[t] = I[t]; sX[t] = xs[t]; }
#pragma unroll
    for (int a = 0; a < 4; ++a)
#pragma unroll
      for (int t = 0; t < 4 - a; ++t) {
        bool sw = sI[t] > sI[t + 1];
        int   i0 = sw ? sI[t + 1] : sI[t];
        int   i1 = sw ? sI[t] : sI[t + 1];
        float x0 = sw ? sX[t + 1] : sX[t];
        float x1 = sw ? sX[t] : sX[t + 1];
        sI[t] = i0; sI[t + 1] = i1; sX[t] = x0; sX[t + 1] = x1;
      }
    float r = 0.0f;
#pragma unroll
    for (int t = 0; t < 5; ++t) r = fmaf(sX[t], dnT[(size_t)sI[t] * C_DIM + lane], r);
    float ze = Xs[lane][sl];
    float t1 = r - ze;                          // z_dl - z_e (rounded, as reference)
    out0[(size_t)b * 65536 + lane * 1024 + hw0 + sl] = ze + t1;   // z_dl_st
    float sq = t1 * t1;
    lsum += (double)sq;
  }

  // wave loss reduce + one atomic per wave
#pragma unroll
  for (int m = 1; m < 64; m <<= 1) lsum += __shfl_xor(lsum, m, 64);
  if (lane == 0) atomicAdd(lossAcc, lsum);

  // ---- Phase 3: coeffs zero + scatter for this block's 16 columns ----
  __syncthreads();
  {
    int rbase = tid >> 2;
    int c0 = (tid & 3) * 4;
#pragma unroll
    for (int p = 0; p < 8; ++p) {
      int rown = p * 64 + rbase;
      float v[4];
#pragma unroll
      for (int u = 0; u < 4; ++u) {
        int slc = c0 + u;
        float val = 0.0f;
#pragma unroll
        for (int t = 0; t < K_SP; ++t)
          val = (IldsI[slc][t] == rown) ? IldsX[slc][t] : val;
        v[u] = val;
      }
      size_t base = (size_t)rown * 65536 + sbase + c0;
      coeffs[base + 0] = v[0];
      coeffs[base + 1] = v[1];
      coeffs[base + 2] = v[2];
      coeffs[base + 3] = v[3];
    }
  }
}

// ---------------------------------------------------------------------------
// Kernel 4: finalize loss
// ---------------------------------------------------------------------------
__global__ void finalize_k(const double* __restrict__ lossAcc, float* __restrict__ out) {
  if (threadIdx.x == 0) {
    float dl = (float)(*lossAcc / 4194304.0);
    out[4194304] = dl + 0.25f * dl;
  }
}

extern "C" void kernel_launch(void* const* d_in, const int* in_sizes, int n_in,
                              void* d_out, int out_size, void* d_ws, size_t ws_size,
                              hipStream_t stream) {
  (void)in_sizes; (void)n_in; (void)out_size; (void)ws_size;
  const float* z    = (const float*)d_in[0];   // (64,64,32,32)
  const float* dict = (const float*)d_in[1];   // (64,512)
  float* out    = (float*)d_out;               // z_dl_st | loss | coeffs
  float* coeffs = out + 4194305;
  float* dn  = (float*)d_ws;
  float* dnT = dn + 32768;
  float* G   = dnT + 32768;
  double* lossAcc = (double*)((char*)d_ws + 1310720);

  prep_norm_k<<<2, 256, 0, stream>>>(dict, dn, dnT, lossAcc);
  prep_gram_k<<<64, 256, 0, stream>>>(dn, G);
  omp_main_k<<<4096, 256, 0, stream>>>(z, dn, dnT, G, out, coeffs, lossAcc);
  finalize_k<<<1, 64, 0, stream>>>(lossAcc, out);
}

// Round 9
// 404.154 us; speedup vs baseline: 2.3401x; 1.0716x over previous
//
#include <hip/hip_runtime.h>
#include <type_traits>

// Problem constants
#define N_ATOMS 512
#define C_DIM   64
#define K_SP    5
#define TS      16      // signals per block
#define HROW    512     // H row stride: H stored [sl][atom], unioned with dn chunk

// R9 = r8 anchor + three bit-exact VALU-issue cuts (kernel is issue-bound:
// 1136 inst/signal model matches 245us phase-2 wall at 55% VALUBusy):
//  1. insertion via uniform branches (readfirstlane(p)) instead of 144 cndmask
//  2. fabs+select-mask fused into one v_and via maskb[8]
//  3. phase-1 GEMM as float2 + elementwise_fma -> v_pk_fma_f32 (2 FMA/inst)
// plus nr-load hoisted right after nsel.

typedef float f32x2 __attribute__((ext_vector_type(2)));

// ---------------------------------------------------------------------------
// Wave64 DPP reductions (pure VALU; r7 win).
// ---------------------------------------------------------------------------
__device__ __forceinline__ unsigned wave_redmax_u32(unsigned u) {
  unsigned t;
  t = (unsigned)__builtin_amdgcn_update_dpp((int)u, (int)u, 0xB1, 0xF, 0xF, false); u = t > u ? t : u;
  t = (unsigned)__builtin_amdgcn_update_dpp((int)u, (int)u, 0x4E, 0xF, 0xF, false); u = t > u ? t : u;
  t = (unsigned)__builtin_amdgcn_update_dpp((int)u, (int)u, 0x141, 0xF, 0xF, false); u = t > u ? t : u;
  t = (unsigned)__builtin_amdgcn_update_dpp((int)u, (int)u, 0x140, 0xF, 0xF, false); u = t > u ? t : u;
  t = (unsigned)__builtin_amdgcn_update_dpp((int)u, (int)u, 0x142, 0xF, 0xF, false); u = t > u ? t : u;
  t = (unsigned)__builtin_amdgcn_update_dpp((int)u, (int)u, 0x143, 0xF, 0xF, false); u = t > u ? t : u;
  return (unsigned)__builtin_amdgcn_readlane((int)u, 63);
}
__device__ __forceinline__ unsigned wave_redmin_u32(unsigned u) {
  unsigned t;
  t = (unsigned)__builtin_amdgcn_update_dpp((int)u, (int)u, 0xB1, 0xF, 0xF, false); u = t < u ? t : u;
  t = (unsigned)__builtin_amdgcn_update_dpp((int)u, (int)u, 0x4E, 0xF, 0xF, false); u = t < u ? t : u;
  t = (unsigned)__builtin_amdgcn_update_dpp((int)u, (int)u, 0x141, 0xF, 0xF, false); u = t < u ? t : u;
  t = (unsigned)__builtin_amdgcn_update_dpp((int)u, (int)u, 0x140, 0xF, 0xF, false); u = t < u ? t : u;
  t = (unsigned)__builtin_amdgcn_update_dpp((int)u, (int)u, 0x142, 0xF, 0xF, false); u = t < u ? t : u;
  t = (unsigned)__builtin_amdgcn_update_dpp((int)u, (int)u, 0x143, 0xF, 0xF, false); u = t < u ? t : u;
  return (unsigned)__builtin_amdgcn_readlane((int)u, 63);
}

// sorted insertion at compile-time position P (taken under a uniform branch)
template<int K, int P>
__device__ __forceinline__ void ins_at(int (&srtI)[4], float (&GrowS)[4][8],
                                       int nsel, const float (&nr)[8]) {
#pragma unroll
  for (int u = K - 1; u > P; --u) {
    srtI[u] = srtI[u - 1];
#pragma unroll
    for (int jb = 0; jb < 8; ++jb) GrowS[u][jb] = GrowS[u - 1][jb];
  }
  srtI[P] = nsel;
#pragma unroll
  for (int jb = 0; jb < 8; ++jb) GrowS[P][jb] = nr[jb];
}

// ---------------------------------------------------------------------------
// Kernel 1: column norms + normalized dictionary (dn) + its transpose (dnT).
// ---------------------------------------------------------------------------
__global__ __launch_bounds__(256) void prep_norm_k(const float* __restrict__ dict,
                                                   float* __restrict__ dn,
                                                   float* __restrict__ dnT,
                                                   double* __restrict__ lossAcc) {
#pragma clang fp contract(off)
  const int n = blockIdx.x * 256 + threadIdx.x;
  if (blockIdx.x == 0 && threadIdx.x == 0) *lossAcc = 0.0;
  if (n >= N_ATOMS) return;
  float s = 0.0f;
  for (int c = 0; c < C_DIM; ++c) {
    float v = dict[c * N_ATOMS + n];
    float sq = v * v;
    s = s + sq;
  }
  float m = fmaxf(sqrtf(s), 1e-10f);
  for (int c = 0; c < C_DIM; ++c) {
    float q = dict[c * N_ATOMS + n] / m;
    dn[c * N_ATOMS + n] = q;
    dnT[n * C_DIM + c] = q;
  }
}

// ---------------------------------------------------------------------------
// Kernel 2: G = dn^T dn (512x512), f32 FMA chain sequential over c.
// ---------------------------------------------------------------------------
__global__ __launch_bounds__(256) void prep_gram_k(const float* __restrict__ dn,
                                                   float* __restrict__ G) {
#pragma clang fp contract(off)
  __shared__ float As[64][64];
  __shared__ float Bs[64][64];
  const int bi = blockIdx.x & 7, bj = blockIdx.x >> 3;
  const int tid = threadIdx.x;
  for (int r = 0; r < 16; ++r) {
    int e = r * 256 + tid;
    int c = e >> 6, i = e & 63;
    As[c][i] = dn[c * N_ATOMS + bi * 64 + i];
    Bs[c][i] = dn[c * N_ATOMS + bj * 64 + i];
  }
  __syncthreads();
  const int ti = tid & 15, tj = tid >> 4;
  float acc[4][4] = {};
  for (int c = 0; c < 64; ++c) {
    float a[4], b[4];
#pragma unroll
    for (int u = 0; u < 4; ++u) { a[u] = As[c][ti * 4 + u]; b[u] = Bs[c][tj * 4 + u]; }
#pragma unroll
    for (int u = 0; u < 4; ++u)
#pragma unroll
      for (int v = 0; v < 4; ++v) acc[u][v] = fmaf(a[u], b[v], acc[u][v]);
  }
  for (int u = 0; u < 4; ++u)
    for (int v = 0; v < 4; ++v)
      G[(size_t)(bi * 64 + ti * 4 + u) * N_ATOMS + bj * 64 + tj * 4 + v] = acc[u][v];
}

// ---------------------------------------------------------------------------
// Kernel 3: fused h_bar GEMM + batched OMP + outputs.
// ---------------------------------------------------------------------------
__global__ __launch_bounds__(256) void omp_main_k(const float* __restrict__ z,
                                                  const float* __restrict__ dn,
                                                  const float* __restrict__ dnT,
                                                  const float* __restrict__ Gm,
                                                  float* __restrict__ out0,
                                                  float* __restrict__ coeffs,
                                                  double* __restrict__ lossAcc) {
#pragma clang fp contract(off)
  __shared__ float Xs[64][16];                       // 4 KB  : Xs[c][sl]
  __shared__ __align__(16) float UB[TS * HROW];      // 32 KB : dn chunk, then H[sl][atom]
  __shared__ int   IldsI[TS][K_SP];
  __shared__ float IldsX[TS][K_SP];

  const int tid   = threadIdx.x;
  const int sbase = blockIdx.x * TS;
  const int b     = sbase >> 10;
  const int hw0   = sbase & 1023;
  const float* zb = z + (size_t)b * 65536;

  // ---- stage Xs (coalesced float4) ----
  {
    int c = tid >> 2, slc = (tid & 3) * 4;
    float4 v = *reinterpret_cast<const float4*>(zb + c * 1024 + hw0 + slc);
    *reinterpret_cast<float4*>(&Xs[c][slc]) = v;
  }

  // ---- Phase 1: GEMM via v_pk_fma_f32 (packed f32, per-lane IEEE-exact).
  // thread: atoms {4*ia+r, 256+4*ia+r}, signals {4*js+u}; acc2[r][0]={u0,u1},
  // acc2[r][1]={u2,u3}.
  const int ia4 = (tid & 63) * 4;
  const int js4 = (tid >> 6) * 4;
  f32x2 acc2[8][2] = {};
#pragma unroll
  for (int cc = 0; cc < 4; ++cc) {
    __syncthreads();
    {
      const float* src = dn + cc * 8192;   // 16 rows x 512
#pragma unroll
      for (int r = 0; r < 8; ++r) {
        int off = (r * 256 + tid) * 4;
        *reinterpret_cast<float4*>(&UB[off]) = *reinterpret_cast<const float4*>(src + off);
      }
    }
    __syncthreads();
#pragma unroll
    for (int c = 0; c < 16; ++c) {
      const float4 xv = *reinterpret_cast<const float4*>(&Xs[cc * 16 + c][js4]);
      const f32x2 x01 = { xv.x, xv.y };
      const f32x2 x23 = { xv.z, xv.w };
      const float4 d0 = *reinterpret_cast<const float4*>(&UB[c * 512 + ia4]);
      const float4 d1 = *reinterpret_cast<const float4*>(&UB[c * 512 + 256 + ia4]);
      const float dv[8] = { d0.x, d0.y, d0.z, d0.w, d1.x, d1.y, d1.z, d1.w };
#pragma unroll
      for (int r = 0; r < 8; ++r) {
        const f32x2 dd = { dv[r], dv[r] };
        acc2[r][0] = __builtin_elementwise_fma(dd, x01, acc2[r][0]);  // seq over c
        acc2[r][1] = __builtin_elementwise_fma(dd, x23, acc2[r][1]);
      }
    }
  }
  __syncthreads();
  // write H[sl][atom]: per signal u, dense float4 (conflict-free)
#pragma unroll
  for (int u = 0; u < 4; ++u) {
    const int sl = js4 + u;
    const int hv = u >> 1, lo = u & 1;
    *reinterpret_cast<float4*>(&UB[sl * HROW + ia4]) =
        make_float4(acc2[0][hv][lo], acc2[1][hv][lo], acc2[2][hv][lo], acc2[3][hv][lo]);
    *reinterpret_cast<float4*>(&UB[sl * HROW + 256 + ia4]) =
        make_float4(acc2[4][hv][lo], acc2[5][hv][lo], acc2[6][hv][lo], acc2[7][hv][lo]);
  }
  __syncthreads();

  // ---- Phase 2: OMP (wave per signal, 4 signals per wave) ----
  const int lane = tid & 63;
  const int wid  = tid >> 6;
  double lsum = 0.0;

  for (int q = 0; q < 4; ++q) {
    const int sl = wid * 4 + q;
    float hb[8];
#pragma unroll
    for (int jb = 0; jb < 8; ++jb) hb[jb] = UB[sl * HROW + lane + 64 * jb];  // lane-consecutive

    unsigned maskb[8];
#pragma unroll
    for (int jb = 0; jb < 8; ++jb) maskb[jb] = 0x7fffffffu;   // fabs-mask, cleared on select

    int   I[K_SP];
    float xs[K_SP];
    float yv[K_SP];
    float Lm[K_SP][K_SP];
    int   srtI[4];
    float GrowS[4][8];

    auto iter = [&](auto KC) {
      constexpr int k = decltype(KC)::value;
      float cur[8];
      if constexpr (k == 1) {
#pragma unroll
        for (int jb = 0; jb < 8; ++jb) cur[jb] = hb[jb];
      } else {
        // xs values aligned to sorted atom order (numpy sums beta j-ascending)
        float xsS[k - 1];
#pragma unroll
        for (int u = 0; u < k - 1; ++u) {
          float xv = 0.0f;
#pragma unroll
          for (int t = 0; t < k - 1; ++t) xv = (I[t] == srtI[u]) ? xs[t] : xv;
          xsS[u] = xv;
        }
#pragma unroll
        for (int jb = 0; jb < 8; ++jb) {
          float beta = 0.0f;
#pragma unroll
          for (int u = 0; u < k - 1; ++u) beta = fmaf(xsS[u], GrowS[u][jb], beta);
          cur[jb] = hb[jb] - beta;
        }
      }
      // masked |.| argmax, first-index tie-break (numpy argmax semantics).
      // maskb holds 0x7fffffff (abs) or 0 (selected) -> one v_and per element.
      unsigned curb[8];
      unsigned mv = 0u;
#pragma unroll
      for (int jb = 0; jb < 8; ++jb) {
        curb[jb] = __float_as_uint(cur[jb]) & maskb[jb];
        mv = curb[jb] > mv ? curb[jb] : mv;
      }
      const unsigned M = wave_redmax_u32(mv);
      unsigned cand = 0x7fffffffu;
#pragma unroll
      for (int jb = 7; jb >= 0; --jb)          // descending: final = smallest idx
        cand = (curb[jb] == M) ? (unsigned)(lane + 64 * jb) : cand;
      const int nsel = (int)wave_redmin_u32(cand);
      I[k - 1] = nsel;
      const int lnn = __builtin_amdgcn_readfirstlane(nsel & 63);
      const int jbn = __builtin_amdgcn_readfirstlane(nsel >> 6);
      {
        // clear the selected slot's mask (uniform if-tree on jbn)
        unsigned em = (lane == lnn) ? 0u : 0xffffffffu;
        if      (jbn == 0) maskb[0] &= em;
        else if (jbn == 1) maskb[1] &= em;
        else if (jbn == 2) maskb[2] &= em;
        else if (jbn == 3) maskb[3] &= em;
        else if (jbn == 4) maskb[4] &= em;
        else if (jbn == 5) maskb[5] &= em;
        else if (jbn == 6) maskb[6] &= em;
        else               maskb[7] &= em;
      }

      // G row of nsel: issue load right after selection (hidden under solves)
      float nr[8];
      if constexpr (k <= 4) {
#pragma unroll
        for (int jb = 0; jb < 8; ++jb) nr[jb] = Gm[(size_t)nsel * N_ATOMS + lane + 64 * jb];
      }

      if constexpr (k > 1) {
        float Gs[k - 1], w[k - 1];
#pragma unroll
        for (int t = 0; t < k - 1; ++t) Gs[t] = Gm[(size_t)I[t] * N_ATOMS + nsel];
#pragma unroll
        for (int t = 0; t < k - 1; ++t) {
          float a = Gs[t];
#pragma unroll
          for (int u = 0; u < t; ++u) a = a - Lm[t][u] * w[u];
          w[t] = a / Lm[t][t];
        }
        float ss = 0.0f;
#pragma unroll
        for (int t = 0; t < k - 1; ++t) { float sq = w[t] * w[t]; ss = ss + sq; }
        float wc = sqrtf(1.0f - ss);
#pragma unroll
        for (int t = 0; t < k - 1; ++t) Lm[k - 1][t] = w[t];
        Lm[k - 1][k - 1] = wc;
      } else {
        Lm[0][0] = 1.0f;
      }
      // forward solve: y[0..k-2] bit-identical to previous iteration
      {
        float a = UB[sl * HROW + nsel];
#pragma unroll
        for (int u = 0; u < k - 1; ++u) a = a - Lm[k - 1][u] * yv[u];
        yv[k - 1] = a / Lm[k - 1][k - 1];
      }
#pragma unroll
      for (int t = k - 1; t >= 0; --t) {
        float a = yv[t];
#pragma unroll
        for (int u = t + 1; u < k; ++u) a = a - Lm[u][t] * xs[u];
        xs[t] = a / Lm[t][t];
      }
      if constexpr (k <= 4) {
        // insertion position p is wave-uniform -> uniform branch tree of movs
        int p = 0;
#pragma unroll
        for (int u = 0; u < k - 1; ++u) p += (srtI[u] < nsel) ? 1 : 0;
        if constexpr (k == 1) {
          ins_at<1, 0>(srtI, GrowS, nsel, nr);
        } else {
          const int pu = __builtin_amdgcn_readfirstlane(p);
          if (pu == 0) ins_at<k, 0>(srtI, GrowS, nsel, nr);
          else {
            if constexpr (k >= 2) {
              if (pu == 1) ins_at<k, 1>(srtI, GrowS, nsel, nr);
              else {
                if constexpr (k >= 3) {
                  if (pu == 2) ins_at<k, 2>(srtI, GrowS, nsel, nr);
                  else {
                    if constexpr (k >= 4) ins_at<k, 3>(srtI, GrowS, nsel, nr);
                  }
                }
              }
            }
          }
        }
      }
    };
    iter(std::integral_constant<int, 1>{});
    iter(std::integral_constant<int, 2>{});
    iter(std::integral_constant<int, 3>{});
    iter(std::integral_constant<int, 4>{});
    iter(std::integral_constant<int, 5>{});

    if (lane == 0) {
#pragma unroll
      for (int t = 0; t < K_SP; ++t) { IldsI[sl][t] = I[t]; IldsX[sl][t] = xs[t]; }
    }

    // recon in sorted-index order (numpy GEMM sums j ascending)
    int sI[5]; float sX[5];
#pragma unroll
    for (int t = 0; t < 5; ++t) { sI[t] = I[t]; sX[t] = xs[t]; }
#pragma unroll
    for (int a = 0; a < 4; ++a)
#pragma unroll
      for (int t = 0; t < 4 - a; ++t) {
        bool sw = sI[t] > sI[t + 1];
        int   i0 = sw ? sI[t + 1] : sI[t];
        int   i1 = sw ? sI[t] : sI[t + 1];
        float x0 = sw ? sX[t + 1] : sX[t];
        float x1 = sw ? sX[t] : sX[t + 1];
        sI[t] = i0; sI[t + 1] = i1; sX[t] = x0; sX[t + 1] = x1;
      }
    float r = 0.0f;
#pragma unroll
    for (int t = 0; t < 5; ++t) r = fmaf(sX[t], dnT[(size_t)sI[t] * C_DIM + lane], r);
    float ze = Xs[lane][sl];
    float t1 = r - ze;                          // z_dl - z_e (rounded, as reference)
    out0[(size_t)b * 65536 + lane * 1024 + hw0 + sl] = ze + t1;   // z_dl_st
    float sq = t1 * t1;
    lsum += (double)sq;
  }

  // wave loss reduce + one atomic per wave
#pragma unroll
  for (int m = 1; m < 64; m <<= 1) lsum += __shfl_xor(lsum, m, 64);
  if (lane == 0) atomicAdd(lossAcc, lsum);

  // ---- Phase 3: coeffs zero + scatter for this block's 16 columns ----
  __syncthreads();
  {
    int rbase = tid >> 2;
    int c0 = (tid & 3) * 4;
#pragma unroll
    for (int p = 0; p < 8; ++p) {
      int rown = p * 64 + rbase;
      float v[4];
#pragma unroll
      for (int u = 0; u < 4; ++u) {
        int slc = c0 + u;
        float val = 0.0f;
#pragma unroll
        for (int t = 0; t < K_SP; ++t)
          val = (IldsI[slc][t] == rown) ? IldsX[slc][t] : val;
        v[u] = val;
      }
      size_t base = (size_t)rown * 65536 + sbase + c0;
      coeffs[base + 0] = v[0];
      coeffs[base + 1] = v[1];
      coeffs[base + 2] = v[2];
      coeffs[base + 3] = v[3];
    }
  }
}

// ---------------------------------------------------------------------------
// Kernel 4: finalize loss
// ---------------------------------------------------------------------------
__global__ void finalize_k(const double* __restrict__ lossAcc, float* __restrict__ out) {
  if (threadIdx.x == 0) {
    float dl = (float)(*lossAcc / 4194304.0);
    out[4194304] = dl + 0.25f * dl;
  }
}

extern "C" void kernel_launch(void* const* d_in, const int* in_sizes, int n_in,
                              void* d_out, int out_size, void* d_ws, size_t ws_size,
                              hipStream_t stream) {
  (void)in_sizes; (void)n_in; (void)out_size; (void)ws_size;
  const float* z    = (const float*)d_in[0];   // (64,64,32,32)
  const float* dict = (const float*)d_in[1];   // (64,512)
  float* out    = (float*)d_out;               // z_dl_st | loss | coeffs
  float* coeffs = out + 4194305;
  float* dn  = (float*)d_ws;
  float* dnT = dn + 32768;
  float* G   = dnT + 32768;
  double* lossAcc = (double*)((char*)d_ws + 1310720);

  prep_norm_k<<<2, 256, 0, stream>>>(dict, dn, dnT, lossAcc);
  prep_gram_k<<<64, 256, 0, stream>>>(dn, G);
  omp_main_k<<<4096, 256, 0, stream>>>(z, dn, dnT, G, out, coeffs, lossAcc);
  finalize_k<<<1, 64, 0, stream>>>(lossAcc, out);
}

// Round 10
// 397.070 us; speedup vs baseline: 2.3818x; 1.0178x over previous
//
#include <hip/hip_runtime.h>
#include <type_traits>

// Problem constants
#define N_ATOMS 512
#define C_DIM   64
#define K_SP    5
#define TS      16      // signals per block
#define HROW    512     // H row stride: H stored [sl][atom], unioned with dn chunk

// R10 = r9 anchor + (1) reciprocal-cached triangular solves in omp_main
// (30 IEEE divides/signal -> 5 divides + 25 muls; ~200 inst/signal saved;
// 1-ulp-class rounding shift, same error class as existing argmax-flip noise)
// + (2) parallel coalesced prep_norm (2-block serial strided version was ~40us
// of the ~129us non-omp gap). Changes are in different kernels => attributable.

typedef float f32x2 __attribute__((ext_vector_type(2)));

// ---------------------------------------------------------------------------
// Wave64 DPP reductions (pure VALU; r7 win).
// ---------------------------------------------------------------------------
__device__ __forceinline__ unsigned wave_redmax_u32(unsigned u) {
  unsigned t;
  t = (unsigned)__builtin_amdgcn_update_dpp((int)u, (int)u, 0xB1, 0xF, 0xF, false); u = t > u ? t : u;
  t = (unsigned)__builtin_amdgcn_update_dpp((int)u, (int)u, 0x4E, 0xF, 0xF, false); u = t > u ? t : u;
  t = (unsigned)__builtin_amdgcn_update_dpp((int)u, (int)u, 0x141, 0xF, 0xF, false); u = t > u ? t : u;
  t = (unsigned)__builtin_amdgcn_update_dpp((int)u, (int)u, 0x140, 0xF, 0xF, false); u = t > u ? t : u;
  t = (unsigned)__builtin_amdgcn_update_dpp((int)u, (int)u, 0x142, 0xF, 0xF, false); u = t > u ? t : u;
  t = (unsigned)__builtin_amdgcn_update_dpp((int)u, (int)u, 0x143, 0xF, 0xF, false); u = t > u ? t : u;
  return (unsigned)__builtin_amdgcn_readlane((int)u, 63);
}
__device__ __forceinline__ unsigned wave_redmin_u32(unsigned u) {
  unsigned t;
  t = (unsigned)__builtin_amdgcn_update_dpp((int)u, (int)u, 0xB1, 0xF, 0xF, false); u = t < u ? t : u;
  t = (unsigned)__builtin_amdgcn_update_dpp((int)u, (int)u, 0x4E, 0xF, 0xF, false); u = t < u ? t : u;
  t = (unsigned)__builtin_amdgcn_update_dpp((int)u, (int)u, 0x141, 0xF, 0xF, false); u = t < u ? t : u;
  t = (unsigned)__builtin_amdgcn_update_dpp((int)u, (int)u, 0x140, 0xF, 0xF, false); u = t < u ? t : u;
  t = (unsigned)__builtin_amdgcn_update_dpp((int)u, (int)u, 0x142, 0xF, 0xF, false); u = t < u ? t : u;
  t = (unsigned)__builtin_amdgcn_update_dpp((int)u, (int)u, 0x143, 0xF, 0xF, false); u = t < u ? t : u;
  return (unsigned)__builtin_amdgcn_readlane((int)u, 63);
}

// sorted insertion at compile-time position P (taken under a uniform branch)
template<int K, int P>
__device__ __forceinline__ void ins_at(int (&srtI)[4], float (&GrowS)[4][8],
                                       int nsel, const float (&nr)[8]) {
#pragma unroll
  for (int u = K - 1; u > P; --u) {
    srtI[u] = srtI[u - 1];
#pragma unroll
    for (int jb = 0; jb < 8; ++jb) GrowS[u][jb] = GrowS[u - 1][jb];
  }
  srtI[P] = nsel;
#pragma unroll
  for (int jb = 0; jb < 8; ++jb) GrowS[P][jb] = nr[jb];
}

// ---------------------------------------------------------------------------
// Kernel 1: column norms + normalized dictionary (dn) + transpose (dnT).
// 8 blocks x 64 lanes; coalesced row loads into LDS tile; per-atom column
// reduced sequentially over c (bit-identical order to the r9 version).
// ---------------------------------------------------------------------------
__global__ __launch_bounds__(64) void prep_norm_k(const float* __restrict__ dict,
                                                  float* __restrict__ dn,
                                                  float* __restrict__ dnT,
                                                  double* __restrict__ lossAcc) {
#pragma clang fp contract(off)
  __shared__ float tile[64][65];    // [c][n], pad avoids transpose conflicts
  const int lane = threadIdx.x;
  const int n0 = blockIdx.x * 64;
  if (blockIdx.x == 0 && lane == 0) *lossAcc = 0.0;
  for (int c = 0; c < C_DIM; ++c)
    tile[c][lane] = dict[c * N_ATOMS + n0 + lane];       // coalesced 256B rows
  float s = 0.0f;
  for (int c = 0; c < C_DIM; ++c) {
    float v = tile[c][lane];
    float sq = v * v;
    s = s + sq;                                          // sequential over c
  }
  float m = fmaxf(sqrtf(s), 1e-10f);
  for (int c = 0; c < C_DIM; ++c) {
    float q = tile[c][lane] / m;
    tile[c][lane] = q;
    dn[c * N_ATOMS + n0 + lane] = q;                     // coalesced
  }
  __syncthreads();
  // dnT rows n0..n0+63 via LDS transpose, float4 stores
  for (int r = 0; r < 16; ++r) {
    int e = r * 64 + lane;
    int nn = e >> 4, cc = (e & 15) * 4;
    float4 v = make_float4(tile[cc][nn], tile[cc + 1][nn], tile[cc + 2][nn], tile[cc + 3][nn]);
    *reinterpret_cast<float4*>(&dnT[(size_t)(n0 + nn) * C_DIM + cc]) = v;
  }
}

// ---------------------------------------------------------------------------
// Kernel 2: G = dn^T dn (512x512), f32 FMA chain sequential over c.
// ---------------------------------------------------------------------------
__global__ __launch_bounds__(256) void prep_gram_k(const float* __restrict__ dn,
                                                   float* __restrict__ G) {
#pragma clang fp contract(off)
  __shared__ float As[64][64];
  __shared__ float Bs[64][64];
  const int bi = blockIdx.x & 7, bj = blockIdx.x >> 3;
  const int tid = threadIdx.x;
  for (int r = 0; r < 16; ++r) {
    int e = r * 256 + tid;
    int c = e >> 6, i = e & 63;
    As[c][i] = dn[c * N_ATOMS + bi * 64 + i];
    Bs[c][i] = dn[c * N_ATOMS + bj * 64 + i];
  }
  __syncthreads();
  const int ti = tid & 15, tj = tid >> 4;
  float acc[4][4] = {};
  for (int c = 0; c < 64; ++c) {
    float a[4], b[4];
#pragma unroll
    for (int u = 0; u < 4; ++u) { a[u] = As[c][ti * 4 + u]; b[u] = Bs[c][tj * 4 + u]; }
#pragma unroll
    for (int u = 0; u < 4; ++u)
#pragma unroll
      for (int v = 0; v < 4; ++v) acc[u][v] = fmaf(a[u], b[v], acc[u][v]);
  }
  for (int u = 0; u < 4; ++u)
    for (int v = 0; v < 4; ++v)
      G[(size_t)(bi * 64 + ti * 4 + u) * N_ATOMS + bj * 64 + tj * 4 + v] = acc[u][v];
}

// ---------------------------------------------------------------------------
// Kernel 3: fused h_bar GEMM + batched OMP + outputs.
// ---------------------------------------------------------------------------
__global__ __launch_bounds__(256) void omp_main_k(const float* __restrict__ z,
                                                  const float* __restrict__ dn,
                                                  const float* __restrict__ dnT,
                                                  const float* __restrict__ Gm,
                                                  float* __restrict__ out0,
                                                  float* __restrict__ coeffs,
                                                  double* __restrict__ lossAcc) {
#pragma clang fp contract(off)
  __shared__ float Xs[64][16];                       // 4 KB  : Xs[c][sl]
  __shared__ __align__(16) float UB[TS * HROW];      // 32 KB : dn chunk, then H[sl][atom]
  __shared__ int   IldsI[TS][K_SP];
  __shared__ float IldsX[TS][K_SP];

  const int tid   = threadIdx.x;
  const int sbase = blockIdx.x * TS;
  const int b     = sbase >> 10;
  const int hw0   = sbase & 1023;
  const float* zb = z + (size_t)b * 65536;

  // ---- stage Xs (coalesced float4) ----
  {
    int c = tid >> 2, slc = (tid & 3) * 4;
    float4 v = *reinterpret_cast<const float4*>(zb + c * 1024 + hw0 + slc);
    *reinterpret_cast<float4*>(&Xs[c][slc]) = v;
  }

  // ---- Phase 1: GEMM via v_pk_fma_f32 (packed f32, per-lane IEEE-exact).
  const int ia4 = (tid & 63) * 4;
  const int js4 = (tid >> 6) * 4;
  f32x2 acc2[8][2] = {};
#pragma unroll
  for (int cc = 0; cc < 4; ++cc) {
    __syncthreads();
    {
      const float* src = dn + cc * 8192;   // 16 rows x 512
#pragma unroll
      for (int r = 0; r < 8; ++r) {
        int off = (r * 256 + tid) * 4;
        *reinterpret_cast<float4*>(&UB[off]) = *reinterpret_cast<const float4*>(src + off);
      }
    }
    __syncthreads();
#pragma unroll
    for (int c = 0; c < 16; ++c) {
      const float4 xv = *reinterpret_cast<const float4*>(&Xs[cc * 16 + c][js4]);
      const f32x2 x01 = { xv.x, xv.y };
      const f32x2 x23 = { xv.z, xv.w };
      const float4 d0 = *reinterpret_cast<const float4*>(&UB[c * 512 + ia4]);
      const float4 d1 = *reinterpret_cast<const float4*>(&UB[c * 512 + 256 + ia4]);
      const float dv[8] = { d0.x, d0.y, d0.z, d0.w, d1.x, d1.y, d1.z, d1.w };
#pragma unroll
      for (int r = 0; r < 8; ++r) {
        const f32x2 dd = { dv[r], dv[r] };
        acc2[r][0] = __builtin_elementwise_fma(dd, x01, acc2[r][0]);  // seq over c
        acc2[r][1] = __builtin_elementwise_fma(dd, x23, acc2[r][1]);
      }
    }
  }
  __syncthreads();
  // write H[sl][atom]: per signal u, dense float4 (conflict-free)
#pragma unroll
  for (int u = 0; u < 4; ++u) {
    const int sl = js4 + u;
    const int hv = u >> 1, lo = u & 1;
    *reinterpret_cast<float4*>(&UB[sl * HROW + ia4]) =
        make_float4(acc2[0][hv][lo], acc2[1][hv][lo], acc2[2][hv][lo], acc2[3][hv][lo]);
    *reinterpret_cast<float4*>(&UB[sl * HROW + 256 + ia4]) =
        make_float4(acc2[4][hv][lo], acc2[5][hv][lo], acc2[6][hv][lo], acc2[7][hv][lo]);
  }
  __syncthreads();

  // ---- Phase 2: OMP (wave per signal, 4 signals per wave) ----
  const int lane = tid & 63;
  const int wid  = tid >> 6;
  double lsum = 0.0;

  for (int q = 0; q < 4; ++q) {
    const int sl = wid * 4 + q;
    float hb[8];
#pragma unroll
    for (int jb = 0; jb < 8; ++jb) hb[jb] = UB[sl * HROW + lane + 64 * jb];  // lane-consecutive

    unsigned maskb[8];
#pragma unroll
    for (int jb = 0; jb < 8; ++jb) maskb[jb] = 0x7fffffffu;   // fabs-mask, cleared on select

    int   I[K_SP];
    float xs[K_SP];
    float yv[K_SP];
    float Lm[K_SP][K_SP];
    float rdv[K_SP];                 // cached 1/Lm[t][t]
    int   srtI[4];
    float GrowS[4][8];

    auto iter = [&](auto KC) {
      constexpr int k = decltype(KC)::value;
      float cur[8];
      if constexpr (k == 1) {
#pragma unroll
        for (int jb = 0; jb < 8; ++jb) cur[jb] = hb[jb];
      } else {
        // xs values aligned to sorted atom order (numpy sums beta j-ascending)
        float xsS[k - 1];
#pragma unroll
        for (int u = 0; u < k - 1; ++u) {
          float xv = 0.0f;
#pragma unroll
          for (int t = 0; t < k - 1; ++t) xv = (I[t] == srtI[u]) ? xs[t] : xv;
          xsS[u] = xv;
        }
#pragma unroll
        for (int jb = 0; jb < 8; ++jb) {
          float beta = 0.0f;
#pragma unroll
          for (int u = 0; u < k - 1; ++u) beta = fmaf(xsS[u], GrowS[u][jb], beta);
          cur[jb] = hb[jb] - beta;
        }
      }
      // masked |.| argmax, first-index tie-break (numpy argmax semantics).
      unsigned curb[8];
      unsigned mv = 0u;
#pragma unroll
      for (int jb = 0; jb < 8; ++jb) {
        curb[jb] = __float_as_uint(cur[jb]) & maskb[jb];
        mv = curb[jb] > mv ? curb[jb] : mv;
      }
      const unsigned M = wave_redmax_u32(mv);
      unsigned cand = 0x7fffffffu;
#pragma unroll
      for (int jb = 7; jb >= 0; --jb)          // descending: final = smallest idx
        cand = (curb[jb] == M) ? (unsigned)(lane + 64 * jb) : cand;
      const int nsel = (int)wave_redmin_u32(cand);
      I[k - 1] = nsel;
      const int lnn = __builtin_amdgcn_readfirstlane(nsel & 63);
      const int jbn = __builtin_amdgcn_readfirstlane(nsel >> 6);
      {
        unsigned em = (lane == lnn) ? 0u : 0xffffffffu;
        if      (jbn == 0) maskb[0] &= em;
        else if (jbn == 1) maskb[1] &= em;
        else if (jbn == 2) maskb[2] &= em;
        else if (jbn == 3) maskb[3] &= em;
        else if (jbn == 4) maskb[4] &= em;
        else if (jbn == 5) maskb[5] &= em;
        else if (jbn == 6) maskb[6] &= em;
        else               maskb[7] &= em;
      }

      // G row of nsel: issue load right after selection (hidden under solves)
      float nr[8];
      if constexpr (k <= 4) {
#pragma unroll
        for (int jb = 0; jb < 8; ++jb) nr[jb] = Gm[(size_t)nsel * N_ATOMS + lane + 64 * jb];
      }

      if constexpr (k > 1) {
        float Gs[k - 1], w[k - 1];
#pragma unroll
        for (int t = 0; t < k - 1; ++t) Gs[t] = Gm[(size_t)I[t] * N_ATOMS + nsel];
#pragma unroll
        for (int t = 0; t < k - 1; ++t) {
          float a = Gs[t];
#pragma unroll
          for (int u = 0; u < t; ++u) a = a - Lm[t][u] * w[u];
          w[t] = a * rdv[t];
        }
        float ss = 0.0f;
#pragma unroll
        for (int t = 0; t < k - 1; ++t) { float sq = w[t] * w[t]; ss = ss + sq; }
        float wc = sqrtf(1.0f - ss);
#pragma unroll
        for (int t = 0; t < k - 1; ++t) Lm[k - 1][t] = w[t];
        Lm[k - 1][k - 1] = wc;
        rdv[k - 1] = 1.0f / wc;      // one IEEE divide per new diagonal
      } else {
        Lm[0][0] = 1.0f;
        rdv[0] = 1.0f;
      }
      // forward solve: y[0..k-2] unchanged from previous iteration
      {
        float a = UB[sl * HROW + nsel];
#pragma unroll
        for (int u = 0; u < k - 1; ++u) a = a - Lm[k - 1][u] * yv[u];
        yv[k - 1] = a * rdv[k - 1];
      }
#pragma unroll
      for (int t = k - 1; t >= 0; --t) {
        float a = yv[t];
#pragma unroll
        for (int u = t + 1; u < k; ++u) a = a - Lm[u][t] * xs[u];
        xs[t] = a * rdv[t];
      }
      if constexpr (k <= 4) {
        // insertion position p is wave-uniform -> uniform branch tree of movs
        int p = 0;
#pragma unroll
        for (int u = 0; u < k - 1; ++u) p += (srtI[u] < nsel) ? 1 : 0;
        if constexpr (k == 1) {
          ins_at<1, 0>(srtI, GrowS, nsel, nr);
        } else {
          const int pu = __builtin_amdgcn_readfirstlane(p);
          if (pu == 0) ins_at<k, 0>(srtI, GrowS, nsel, nr);
          else {
            if constexpr (k >= 2) {
              if (pu == 1) ins_at<k, 1>(srtI, GrowS, nsel, nr);
              else {
                if constexpr (k >= 3) {
                  if (pu == 2) ins_at<k, 2>(srtI, GrowS, nsel, nr);
                  else {
                    if constexpr (k >= 4) ins_at<k, 3>(srtI, GrowS, nsel, nr);
                  }
                }
              }
            }
          }
        }
      }
    };
    iter(std::integral_constant<int, 1>{});
    iter(std::integral_constant<int, 2>{});
    iter(std::integral_constant<int, 3>{});
    iter(std::integral_constant<int, 4>{});
    iter(std::integral_constant<int, 5>{});

    if (lane == 0) {
#pragma unroll
      for (int t = 0; t < K_SP; ++t) { IldsI[sl][t] = I[t]; IldsX[sl][t] = xs[t]; }
    }

    // recon in sorted-index order (numpy GEMM sums j ascending)
    int sI[5]; float sX[5];
#pragma unroll
    for (int t = 0; t < 5; ++t) { sI[t] = I[t]; sX[t] = xs[t]; }
#pragma unroll
    for (int a = 0; a < 4; ++a)
#pragma unroll
      for (int t = 0; t < 4 - a; ++t) {
        bool sw = sI[t] > sI[t + 1];
        int   i0 = sw ? sI[t + 1] : sI[t];
        int   i1 = sw ? sI[t] : sI[t + 1];
        float x0 = sw ? sX[t + 1] : sX[t];
        float x1 = sw ? sX[t] : sX[t + 1];
        sI[t] = i0; sI[t + 1] = i1; sX[t] = x0; sX[t + 1] = x1;
      }
    float r = 0.0f;
#pragma unroll
    for (int t = 0; t < 5; ++t) r = fmaf(sX[t], dnT[(size_t)sI[t] * C_DIM + lane], r);
    float ze = Xs[lane][sl];
    float t1 = r - ze;                          // z_dl - z_e (rounded, as reference)
    out0[(size_t)b * 65536 + lane * 1024 + hw0 + sl] = ze + t1;   // z_dl_st
    float sq = t1 * t1;
    lsum += (double)sq;
  }

  // wave loss reduce + one atomic per wave
#pragma unroll
  for (int m = 1; m < 64; m <<= 1) lsum += __shfl_xor(lsum, m, 64);
  if (lane == 0) atomicAdd(lossAcc, lsum);

  // ---- Phase 3: coeffs zero + scatter for this block's 16 columns ----
  __syncthreads();
  {
    int rbase = tid >> 2;
    int c0 = (tid & 3) * 4;
#pragma unroll
    for (int p = 0; p < 8; ++p) {
      int rown = p * 64 + rbase;
      float v[4];
#pragma unroll
      for (int u = 0; u < 4; ++u) {
        int slc = c0 + u;
        float val = 0.0f;
#pragma unroll
        for (int t = 0; t < K_SP; ++t)
          val = (IldsI[slc][t] == rown) ? IldsX[slc][t] : val;
        v[u] = val;
      }
      size_t base = (size_t)rown * 65536 + sbase + c0;
      coeffs[base + 0] = v[0];
      coeffs[base + 1] = v[1];
      coeffs[base + 2] = v[2];
      coeffs[base + 3] = v[3];
    }
  }
}

// ---------------------------------------------------------------------------
// Kernel 4: finalize loss
// ---------------------------------------------------------------------------
__global__ void finalize_k(const double* __restrict__ lossAcc, float* __restrict__ out) {
  if (threadIdx.x == 0) {
    float dl = (float)(*lossAcc / 4194304.0);
    out[4194304] = dl + 0.25f * dl;
  }
}

extern "C" void kernel_launch(void* const* d_in, const int* in_sizes, int n_in,
                              void* d_out, int out_size, void* d_ws, size_t ws_size,
                              hipStream_t stream) {
  (void)in_sizes; (void)n_in; (void)out_size; (void)ws_size;
  const float* z    = (const float*)d_in[0];   // (64,64,32,32)
  const float* dict = (const float*)d_in[1];   // (64,512)
  float* out    = (float*)d_out;               // z_dl_st | loss | coeffs
  float* coeffs = out + 4194305;
  float* dn  = (float*)d_ws;
  float* dnT = dn + 32768;
  float* G   = dnT + 32768;
  double* lossAcc = (double*)((char*)d_ws + 1310720);

  prep_norm_k<<<8, 64, 0, stream>>>(dict, dn, dnT, lossAcc);
  prep_gram_k<<<64, 256, 0, stream>>>(dn, G);
  omp_main_k<<<4096, 256, 0, stream>>>(z, dn, dnT, G, out, coeffs, lossAcc);
  finalize_k<<<1, 64, 0, stream>>>(lossAcc, out);
}